// Round 11
// baseline (569.815 us; speedup 1.0000x reference)
//
#include <hip/hip_runtime.h>
#include <hip/hip_bf16.h>

// Problem dims (fixed)
#define Bdim 16
#define Sdim 512
#define Ddim 512
#define Hdim 8
#define DKdim 64
#define Fdim 2048
#define Mrows (Bdim * Sdim)   // 8192

typedef __attribute__((ext_vector_type(8))) short  frag16;   // 8 bf16 (4 VGPRs)
typedef __attribute__((ext_vector_type(4))) float  f32x4;    // MFMA acc
typedef __attribute__((ext_vector_type(8))) unsigned short ushort8;
typedef __attribute__((ext_vector_type(4))) unsigned short ushort4v;

// raw 2^x (v_exp_f32); fallback keeps semantics
#if defined(__has_builtin)
#  if __has_builtin(__builtin_amdgcn_exp2f)
#    define EXP2(x) __builtin_amdgcn_exp2f(x)
#  endif
#endif
#ifndef EXP2
#  define EXP2(x) __expf((x) * 0.6931471805599453f)
#endif
#define SC2 0.18033688011112042f   // 0.125 * log2(e)

// round-to-nearest-even fp32 -> bf16 (finite data)
__device__ __forceinline__ unsigned short f2b(float x) {
    union { float f; unsigned int u; } v; v.f = x;
    unsigned int r = (v.u + 0x7FFFu + ((v.u >> 16) & 1u)) >> 16;
    return (unsigned short)r;
}

// ---------------------------------------------------------------------------
// bf16 MFMA GEMM, 128x128 tile (used for FFN1, N=2048).
// XCD-chunked swizzle + 2-phase double-buffered K-loop.
// ---------------------------------------------------------------------------
__global__ __launch_bounds__(256) void gemm_mfma(
    const __hip_bfloat16* __restrict__ A, const __hip_bfloat16* __restrict__ Bt,
    const float* __restrict__ bias, const float* __restrict__ R,
    float* __restrict__ Cf, unsigned short* __restrict__ Cb,
    int M, int N, int K, int do_relu)
{
    __shared__ short As[2][128 * 32];
    __shared__ short Bs[2][128 * 32];

    const int t = threadIdx.x;
    const int lane = t & 63;
    const int wave = t >> 6;

    // XCD-aware chunked swizzle (grid size divisible by 8)
    const int gx = gridDim.x;
    const int nb = gx * gridDim.y;
    const int lid = blockIdx.x + gx * blockIdx.y;
    const int wid = (lid & 7) * (nb >> 3) + (lid >> 3);
    const int bm = (wid / gx) * 128;
    const int bn = (wid % gx) * 128;

    const int wm = (wave >> 1) * 64;
    const int wn = (wave & 1) * 64;

    f32x4 acc[4][4] = {};
    const int lrow = lane >> 2;
    const int lcol = (lane & 3) * 8;

    auto stage = [&](int k0, int buf) {
#pragma unroll
        for (int i = 0; i < 2; ++i) {
            const int chunk = wave * 2 + i;
            const int row = chunk * 16 + lrow;
            const __hip_bfloat16* ga = A + (size_t)(bm + row) * K + k0 + lcol;
            const __hip_bfloat16* gb = Bt + (size_t)(bn + row) * K + k0 + lcol;
            __builtin_amdgcn_global_load_lds(
                (const __attribute__((address_space(1))) unsigned int*)ga,
                (__attribute__((address_space(3))) unsigned int*)(&As[buf][chunk * 512]),
                16, 0, 0);
            __builtin_amdgcn_global_load_lds(
                (const __attribute__((address_space(1))) unsigned int*)gb,
                (__attribute__((address_space(3))) unsigned int*)(&Bs[buf][chunk * 512]),
                16, 0, 0);
        }
    };

    const int fr = lane & 15;
    const int quad = lane >> 4;
    const int nk = K >> 5;

    stage(0, 0);
    __syncthreads();

    for (int it = 0; it < nk; ++it) {
        const int buf = it & 1;
        if (it + 1 < nk) stage((it + 1) << 5, buf ^ 1);
        frag16 af[4], bfr[4];
#pragma unroll
        for (int i = 0; i < 4; ++i) {
            af[i]  = *(const frag16*)(&As[buf][(wm + i * 16 + fr) * 32 + quad * 8]);
            bfr[i] = *(const frag16*)(&Bs[buf][(wn + i * 16 + fr) * 32 + quad * 8]);
        }
#pragma unroll
        for (int mi = 0; mi < 4; ++mi)
#pragma unroll
            for (int ni = 0; ni < 4; ++ni)
                acc[mi][ni] = __builtin_amdgcn_mfma_f32_16x16x32_bf16(
                    af[mi], bfr[ni], acc[mi][ni], 0, 0, 0);
        __syncthreads();
    }

#pragma unroll
    for (int mi = 0; mi < 4; ++mi) {
#pragma unroll
        for (int r = 0; r < 4; ++r) {
            const int m = bm + wm + mi * 16 + quad * 4 + r;
#pragma unroll
            for (int ni = 0; ni < 4; ++ni) {
                const int n = bn + wn + ni * 16 + fr;
                float v = acc[mi][ni][r] + bias[n];
                if (R) v += R[(size_t)m * N + n];
                if (do_relu) v = fmaxf(v, 0.f);
                if (Cf) Cf[(size_t)m * N + n] = v;
                if (Cb) Cb[(size_t)m * N + n] = f2b(v);
            }
        }
    }
}

// ---------------------------------------------------------------------------
// bf16 MFMA GEMM, 128x64 tile, N=512 fixed, BK=64 (16 MFMA per barrier).
// XOR-swizzled LDS (source pre-swizzle + read-side XOR). Dual-mode via z:
// z=0: A0@B0^T+bias0 -> Cb / Cf(+R);  z=1: A1@B1^T+bias1 -> CbT (Vt layout)
// ---------------------------------------------------------------------------
__global__ __launch_bounds__(256) void gemm_n64(
    const unsigned short* __restrict__ A0, const unsigned short* __restrict__ A1,
    const unsigned short* __restrict__ B0, const unsigned short* __restrict__ B1,
    const float* __restrict__ bias0, const float* __restrict__ bias1,
    const float* __restrict__ R, float* __restrict__ Cf,
    unsigned short* __restrict__ Cb, unsigned short* __restrict__ CbT,
    int K)
{
    const int NN = 512;
    __shared__ short As[2][128 * 64];   // 32 KB
    __shared__ short Bs[2][64 * 64];    // 16 KB

    const int trans = blockIdx.z;
    const unsigned short* A  = trans ? A1 : A0;
    const unsigned short* Bt = trans ? B1 : B0;
    const float* bias        = trans ? bias1 : bias0;

    const int t = threadIdx.x;
    const int lane = t & 63;
    const int wave = t >> 6;

    const int lid = blockIdx.x + 8 * blockIdx.y;          // 0..511
    const int wid = (lid & 7) * 64 + (lid >> 3);
    const int bm = (wid >> 3) * 128;
    const int bn = (wid & 7) * 64;

    const int wm = (wave >> 1) * 64;
    const int wn = (wave & 1) * 32;

    f32x4 acc[4][2] = {};

    const int srcslot = (((lane & 7) ^ (lane >> 3)) << 3);
    const int rsub = lane >> 3;

    auto stage = [&](int k0, int buf) {
#pragma unroll
        for (int i = 0; i < 4; ++i) {
            const int row = i * 32 + wave * 8 + rsub;
            const unsigned short* ga = A + (size_t)(bm + row) * K + k0 + srcslot;
            __builtin_amdgcn_global_load_lds(
                (const __attribute__((address_space(1))) unsigned int*)ga,
                (__attribute__((address_space(3))) unsigned int*)(&As[buf][(i * 256 + wave * 64) * 8]),
                16, 0, 0);
        }
#pragma unroll
        for (int i = 0; i < 2; ++i) {
            const int row = i * 32 + wave * 8 + rsub;
            const unsigned short* gb = Bt + (size_t)(bn + row) * K + k0 + srcslot;
            __builtin_amdgcn_global_load_lds(
                (const __attribute__((address_space(1))) unsigned int*)gb,
                (__attribute__((address_space(3))) unsigned int*)(&Bs[buf][(i * 256 + wave * 64) * 8]),
                16, 0, 0);
        }
    };

    const int fr = lane & 15;
    const int quad = lane >> 4;
    const int sw = (fr & 7) << 3;
    const int nk = K >> 6;

    stage(0, 0);
    __syncthreads();

    for (int it = 0; it < nk; ++it) {
        const int buf = it & 1;
        if (it + 1 < nk) stage((it + 1) << 6, buf ^ 1);
        frag16 af[2][4], bfr[2][2];
#pragma unroll
        for (int ks = 0; ks < 2; ++ks) {
            const int col = (ks * 32 + quad * 8) ^ sw;
#pragma unroll
            for (int i = 0; i < 4; ++i)
                af[ks][i] = *(const frag16*)(&As[buf][(wm + i * 16 + fr) * 64 + col]);
#pragma unroll
            for (int i = 0; i < 2; ++i)
                bfr[ks][i] = *(const frag16*)(&Bs[buf][(wn + i * 16 + fr) * 64 + col]);
        }
#pragma unroll
        for (int ks = 0; ks < 2; ++ks)
#pragma unroll
            for (int mi = 0; mi < 4; ++mi)
#pragma unroll
                for (int ni = 0; ni < 2; ++ni)
                    acc[mi][ni] = __builtin_amdgcn_mfma_f32_16x16x32_bf16(
                        af[ks][mi], bfr[ks][ni], acc[mi][ni], 0, 0, 0);
        __syncthreads();
    }

    if (trans) {
#pragma unroll
        for (int mi = 0; mi < 4; ++mi)
#pragma unroll
            for (int ni = 0; ni < 2; ++ni) {
                const int m = bm + wm + mi * 16 + quad * 4;
                const int n = bn + wn + ni * 16 + fr;
                ushort4v o;
#pragma unroll
                for (int r = 0; r < 4; ++r) o[r] = f2b(acc[mi][ni][r] + bias[n]);
                const int bb = m >> 9, s = m & 511;
                const int hh = n >> 6, dd = n & 63;
                *(ushort4v*)(CbT + (((size_t)((bb * Hdim + hh) * DKdim + dd)) << 9) + s) = o;
            }
        return;
    }

#pragma unroll
    for (int mi = 0; mi < 4; ++mi) {
#pragma unroll
        for (int r = 0; r < 4; ++r) {
            const int m = bm + wm + mi * 16 + quad * 4 + r;
#pragma unroll
            for (int ni = 0; ni < 2; ++ni) {
                const int n = bn + wn + ni * 16 + fr;
                float v = acc[mi][ni][r] + bias[n];
                if (R) v += R[(size_t)m * NN + n];
                if (Cf) Cf[(size_t)m * NN + n] = v;
                if (Cb) Cb[(size_t)m * NN + n] = f2b(v);
            }
        }
    }
}

// ---------------------------------------------------------------------------
// Generic SPLIT-K=2 GEMM, 128x64 tile, N=512 fixed, fp32 out.
// z=0: K in [0,KH)   -> C0 = acc + bias + R
// z=1: K in [KH,2KH) -> C1 = acc   (raw partial; following LN fuses C0+C1)
// ---------------------------------------------------------------------------
__global__ __launch_bounds__(256) void gemm_splitk(
    const unsigned short* __restrict__ A, const unsigned short* __restrict__ Bt,
    const float* __restrict__ bias, const float* __restrict__ R,
    float* __restrict__ C0, float* __restrict__ C1,
    int K, int KH)
{
    __shared__ short As[2][128 * 64];
    __shared__ short Bs[2][64 * 64];

    const int z = blockIdx.z;
    const int kb0 = z * KH;

    const int t = threadIdx.x;
    const int lane = t & 63;
    const int wave = t >> 6;

    const int lid = blockIdx.x + 8 * blockIdx.y;
    const int wid = (lid & 7) * 64 + (lid >> 3);
    const int bm = (wid >> 3) * 128;
    const int bn = (wid & 7) * 64;

    const int wm = (wave >> 1) * 64;
    const int wn = (wave & 1) * 32;

    f32x4 acc[4][2] = {};
    const int srcslot = (((lane & 7) ^ (lane >> 3)) << 3);
    const int rsub = lane >> 3;

    auto stage = [&](int k0, int buf) {
#pragma unroll
        for (int i = 0; i < 4; ++i) {
            const int row = i * 32 + wave * 8 + rsub;
            const unsigned short* ga = A + (size_t)(bm + row) * K + k0 + srcslot;
            __builtin_amdgcn_global_load_lds(
                (const __attribute__((address_space(1))) unsigned int*)ga,
                (__attribute__((address_space(3))) unsigned int*)(&As[buf][(i * 256 + wave * 64) * 8]),
                16, 0, 0);
        }
#pragma unroll
        for (int i = 0; i < 2; ++i) {
            const int row = i * 32 + wave * 8 + rsub;
            const unsigned short* gb = Bt + (size_t)(bn + row) * K + k0 + srcslot;
            __builtin_amdgcn_global_load_lds(
                (const __attribute__((address_space(1))) unsigned int*)gb,
                (__attribute__((address_space(3))) unsigned int*)(&Bs[buf][(i * 256 + wave * 64) * 8]),
                16, 0, 0);
        }
    };

    const int fr = lane & 15;
    const int quad = lane >> 4;
    const int sw = (fr & 7) << 3;
    const int nk = KH >> 6;

    stage(kb0, 0);
    __syncthreads();

    for (int it = 0; it < nk; ++it) {
        const int buf = it & 1;
        if (it + 1 < nk) stage(kb0 + ((it + 1) << 6), buf ^ 1);
        frag16 af[2][4], bfr[2][2];
#pragma unroll
        for (int ks = 0; ks < 2; ++ks) {
            const int col = (ks * 32 + quad * 8) ^ sw;
#pragma unroll
            for (int i = 0; i < 4; ++i)
                af[ks][i] = *(const frag16*)(&As[buf][(wm + i * 16 + fr) * 64 + col]);
#pragma unroll
            for (int i = 0; i < 2; ++i)
                bfr[ks][i] = *(const frag16*)(&Bs[buf][(wn + i * 16 + fr) * 64 + col]);
        }
#pragma unroll
        for (int ks = 0; ks < 2; ++ks)
#pragma unroll
            for (int mi = 0; mi < 4; ++mi)
#pragma unroll
                for (int ni = 0; ni < 2; ++ni)
                    acc[mi][ni] = __builtin_amdgcn_mfma_f32_16x16x32_bf16(
                        af[ks][mi], bfr[ks][ni], acc[mi][ni], 0, 0, 0);
        __syncthreads();
    }

#pragma unroll
    for (int mi = 0; mi < 4; ++mi) {
#pragma unroll
        for (int r = 0; r < 4; ++r) {
            const int m = bm + wm + mi * 16 + quad * 4 + r;
#pragma unroll
            for (int ni = 0; ni < 2; ++ni) {
                const int n = bn + wn + ni * 16 + fr;
                if (z == 0)
                    C0[(size_t)m * 512 + n] = acc[mi][ni][r] + bias[n] + R[(size_t)m * 512 + n];
                else
                    C1[(size_t)m * 512 + n] = acc[mi][ni][r];
            }
        }
    }
}

// ---------------------------------------------------------------------------
// 4-way KV projection: z in 0..3 selects {L0-K, L0-V(trans), L1-K, L1-V(trans)}.
// Same verified BK=64 swizzled core as gemm_n64; K fixed at 512.
// ---------------------------------------------------------------------------
__global__ __launch_bounds__(256) void gemm_kv4(
    const unsigned short* __restrict__ Ya, const unsigned short* __restrict__ Xa,
    const unsigned short* __restrict__ BtK0, const unsigned short* __restrict__ BtV0,
    const unsigned short* __restrict__ BtK1, const unsigned short* __restrict__ BtV1,
    const float* __restrict__ bk0, const float* __restrict__ bv0,
    const float* __restrict__ bk1, const float* __restrict__ bv1,
    unsigned short* __restrict__ K0, unsigned short* __restrict__ V0t,
    unsigned short* __restrict__ K1, unsigned short* __restrict__ V1t)
{
    const int K = 512;
    __shared__ short As[2][128 * 64];
    __shared__ short Bs[2][64 * 64];

    const int z = blockIdx.z;
    const unsigned short* A  = (z < 2) ? Ya : Xa;
    const unsigned short* Bt = (z == 0) ? BtK0 : (z == 1) ? BtV0 : (z == 2) ? BtK1 : BtV1;
    const float* bias        = (z == 0) ? bk0 : (z == 1) ? bv0 : (z == 2) ? bk1 : bv1;
    const int trans = z & 1;

    const int t = threadIdx.x;
    const int lane = t & 63;
    const int wave = t >> 6;

    const int lid = blockIdx.x + 8 * blockIdx.y;
    const int wid = (lid & 7) * 64 + (lid >> 3);
    const int bm = (wid >> 3) * 128;
    const int bn = (wid & 7) * 64;

    const int wm = (wave >> 1) * 64;
    const int wn = (wave & 1) * 32;

    f32x4 acc[4][2] = {};
    const int srcslot = (((lane & 7) ^ (lane >> 3)) << 3);
    const int rsub = lane >> 3;

    auto stage = [&](int k0, int buf) {
#pragma unroll
        for (int i = 0; i < 4; ++i) {
            const int row = i * 32 + wave * 8 + rsub;
            const unsigned short* ga = A + (size_t)(bm + row) * K + k0 + srcslot;
            __builtin_amdgcn_global_load_lds(
                (const __attribute__((address_space(1))) unsigned int*)ga,
                (__attribute__((address_space(3))) unsigned int*)(&As[buf][(i * 256 + wave * 64) * 8]),
                16, 0, 0);
        }
#pragma unroll
        for (int i = 0; i < 2; ++i) {
            const int row = i * 32 + wave * 8 + rsub;
            const unsigned short* gb = Bt + (size_t)(bn + row) * K + k0 + srcslot;
            __builtin_amdgcn_global_load_lds(
                (const __attribute__((address_space(1))) unsigned int*)gb,
                (__attribute__((address_space(3))) unsigned int*)(&Bs[buf][(i * 256 + wave * 64) * 8]),
                16, 0, 0);
        }
    };

    const int fr = lane & 15;
    const int quad = lane >> 4;
    const int sw = (fr & 7) << 3;
    const int nk = K >> 6;

    stage(0, 0);
    __syncthreads();

    for (int it = 0; it < nk; ++it) {
        const int buf = it & 1;
        if (it + 1 < nk) stage((it + 1) << 6, buf ^ 1);
        frag16 af[2][4], bfr[2][2];
#pragma unroll
        for (int ks = 0; ks < 2; ++ks) {
            const int col = (ks * 32 + quad * 8) ^ sw;
#pragma unroll
            for (int i = 0; i < 4; ++i)
                af[ks][i] = *(const frag16*)(&As[buf][(wm + i * 16 + fr) * 64 + col]);
#pragma unroll
            for (int i = 0; i < 2; ++i)
                bfr[ks][i] = *(const frag16*)(&Bs[buf][(wn + i * 16 + fr) * 64 + col]);
        }
#pragma unroll
        for (int ks = 0; ks < 2; ++ks)
#pragma unroll
            for (int mi = 0; mi < 4; ++mi)
#pragma unroll
                for (int ni = 0; ni < 2; ++ni)
                    acc[mi][ni] = __builtin_amdgcn_mfma_f32_16x16x32_bf16(
                        af[ks][mi], bfr[ks][ni], acc[mi][ni], 0, 0, 0);
        __syncthreads();
    }

    if (trans) {
        unsigned short* CbT = (z == 1) ? V0t : V1t;
#pragma unroll
        for (int mi = 0; mi < 4; ++mi)
#pragma unroll
            for (int ni = 0; ni < 2; ++ni) {
                const int m = bm + wm + mi * 16 + quad * 4;
                const int n = bn + wn + ni * 16 + fr;
                ushort4v o;
#pragma unroll
                for (int r = 0; r < 4; ++r) o[r] = f2b(acc[mi][ni][r] + bias[n]);
                const int bb = m >> 9, s = m & 511;
                const int hh = n >> 6, dd = n & 63;
                *(ushort4v*)(CbT + (((size_t)((bb * Hdim + hh) * DKdim + dd)) << 9) + s) = o;
            }
    } else {
        unsigned short* Cb = (z == 0) ? K0 : K1;
#pragma unroll
        for (int mi = 0; mi < 4; ++mi)
#pragma unroll
            for (int r = 0; r < 4; ++r) {
                const int m = bm + wm + mi * 16 + quad * 4 + r;
#pragma unroll
                for (int ni = 0; ni < 2; ++ni) {
                    const int n = bn + wn + ni * 16 + fr;
                    Cb[(size_t)m * 512 + n] = f2b(acc[mi][ni][r] + bias[n]);
                }
            }
    }
}

// ---------------------------------------------------------------------------
// Dual O-projection with SPLIT-K=2: z = layer*2 + khalf. K=512, KH=256.
// khalf=0: C = acc + bias + R; khalf=1: P = acc (raw partial for LN fuse).
// ---------------------------------------------------------------------------
__global__ __launch_bounds__(256) void gemm_o2(
    const unsigned short* __restrict__ A0, const unsigned short* __restrict__ A1,
    const unsigned short* __restrict__ B0, const unsigned short* __restrict__ B1,
    const float* __restrict__ bias0, const float* __restrict__ bias1,
    const float* __restrict__ R0, const float* __restrict__ R1,
    float* __restrict__ C0, float* __restrict__ C1,
    float* __restrict__ P0, float* __restrict__ P1)
{
    const int K = 512, KH = 256;
    __shared__ short As[2][128 * 64];
    __shared__ short Bs[2][64 * 64];

    const int zl = blockIdx.z >> 1, kh = blockIdx.z & 1;
    const unsigned short* A  = zl ? A1 : A0;
    const unsigned short* Bt = zl ? B1 : B0;
    const float* bias        = zl ? bias1 : bias0;
    const float* R           = zl ? R1 : R0;
    float* Cf                = kh ? (zl ? P1 : P0) : (zl ? C1 : C0);
    const int kb0 = kh * KH;

    const int t = threadIdx.x;
    const int lane = t & 63;
    const int wave = t >> 6;

    const int lid = blockIdx.x + 8 * blockIdx.y;
    const int wid = (lid & 7) * 64 + (lid >> 3);
    const int bm = (wid >> 3) * 128;
    const int bn = (wid & 7) * 64;

    const int wm = (wave >> 1) * 64;
    const int wn = (wave & 1) * 32;

    f32x4 acc[4][2] = {};
    const int srcslot = (((lane & 7) ^ (lane >> 3)) << 3);
    const int rsub = lane >> 3;

    auto stage = [&](int k0, int buf) {
#pragma unroll
        for (int i = 0; i < 4; ++i) {
            const int row = i * 32 + wave * 8 + rsub;
            const unsigned short* ga = A + (size_t)(bm + row) * K + k0 + srcslot;
            __builtin_amdgcn_global_load_lds(
                (const __attribute__((address_space(1))) unsigned int*)ga,
                (__attribute__((address_space(3))) unsigned int*)(&As[buf][(i * 256 + wave * 64) * 8]),
                16, 0, 0);
        }
#pragma unroll
        for (int i = 0; i < 2; ++i) {
            const int row = i * 32 + wave * 8 + rsub;
            const unsigned short* gb = Bt + (size_t)(bn + row) * K + k0 + srcslot;
            __builtin_amdgcn_global_load_lds(
                (const __attribute__((address_space(1))) unsigned int*)gb,
                (__attribute__((address_space(3))) unsigned int*)(&Bs[buf][(i * 256 + wave * 64) * 8]),
                16, 0, 0);
        }
    };

    const int fr = lane & 15;
    const int quad = lane >> 4;
    const int sw = (fr & 7) << 3;
    const int nk = KH >> 6;   // 4

    stage(kb0, 0);
    __syncthreads();

    for (int it = 0; it < nk; ++it) {
        const int buf = it & 1;
        if (it + 1 < nk) stage(kb0 + ((it + 1) << 6), buf ^ 1);
        frag16 af[2][4], bfr[2][2];
#pragma unroll
        for (int ks = 0; ks < 2; ++ks) {
            const int col = (ks * 32 + quad * 8) ^ sw;
#pragma unroll
            for (int i = 0; i < 4; ++i)
                af[ks][i] = *(const frag16*)(&As[buf][(wm + i * 16 + fr) * 64 + col]);
#pragma unroll
            for (int i = 0; i < 2; ++i)
                bfr[ks][i] = *(const frag16*)(&Bs[buf][(wn + i * 16 + fr) * 64 + col]);
        }
#pragma unroll
        for (int ks = 0; ks < 2; ++ks)
#pragma unroll
            for (int mi = 0; mi < 4; ++mi)
#pragma unroll
                for (int ni = 0; ni < 2; ++ni)
                    acc[mi][ni] = __builtin_amdgcn_mfma_f32_16x16x32_bf16(
                        af[ks][mi], bfr[ks][ni], acc[mi][ni], 0, 0, 0);
        __syncthreads();
    }

#pragma unroll
    for (int mi = 0; mi < 4; ++mi) {
#pragma unroll
        for (int r = 0; r < 4; ++r) {
            const int m = bm + wm + mi * 16 + quad * 4 + r;
#pragma unroll
            for (int ni = 0; ni < 2; ++ni) {
                const int n = bn + wn + ni * 16 + fr;
                float v = acc[mi][ni][r];
                if (kh == 0) v += bias[n] + R[(size_t)m * 512 + n];
                Cf[(size_t)m * 512 + n] = v;
            }
        }
    }
}

// ---------------------------------------------------------------------------
// fp32 -> bf16 convert, dual-source (two tensors in one launch)
// ---------------------------------------------------------------------------
__global__ __launch_bounds__(256) void conv_b2(
    const float* __restrict__ X0, unsigned short* __restrict__ Y0,
    const float* __restrict__ X1, unsigned short* __restrict__ Y1,
    int halfBlocks)
{
    const int bid = blockIdx.x;
    const float* X = (bid < halfBlocks) ? X0 : X1;
    unsigned short* Y = (bid < halfBlocks) ? Y0 : Y1;
    const int lb = (bid < halfBlocks) ? bid : bid - halfBlocks;
    const size_t i = ((size_t)lb * 256 + threadIdx.x) * 8;
    float4 a = *(const float4*)(X + i);
    float4 b = *(const float4*)(X + i + 4);
    ushort8 o;
    o[0] = f2b(a.x); o[1] = f2b(a.y); o[2] = f2b(a.z); o[3] = f2b(a.w);
    o[4] = f2b(b.x); o[5] = f2b(b.y); o[6] = f2b(b.z); o[7] = f2b(b.w);
    *(ushort8*)(Y + i) = o;
}

// ---------------------------------------------------------------------------
// ALL weight transposes fused: 1600 tiles of 64x64, [K,N] fp32 -> [N,K] bf16
// ---------------------------------------------------------------------------
__global__ __launch_bounds__(256) void wtrans_all(
    const float* __restrict__ Wk, const float* __restrict__ Wv,
    const float* __restrict__ Wo, const float* __restrict__ W1,
    const float* __restrict__ W2, unsigned short* __restrict__ dst)
{
    const int bid = blockIdx.x;
    const float* src; unsigned short* d; int K, N, tk, tn;
    if (bid < 576) {
        const int mat = bid >> 6, tile = bid & 63;
        const int l = mat / 3, wch = mat % 3;
        const float* W = (wch == 0) ? Wk : (wch == 1) ? Wv : Wo;
        src = W + (size_t)l * 262144;
        d = dst + (size_t)mat * 262144;
        K = 512; N = 512; tn = tile & 7; tk = tile >> 3;
    } else if (bid < 1088) {
        const int idx = bid - 576, l2 = idx >> 8, tile = idx & 255;
        src = W1 + (size_t)(l2 * 2) * (512 * 2048);
        d = dst + 9 * 262144 + (size_t)l2 * (512 * 2048);
        K = 512; N = 2048; tn = tile & 31; tk = tile >> 5;
    } else {
        const int idx = bid - 1088, l2 = idx >> 8, tile = idx & 255;
        src = W2 + (size_t)(l2 * 2) * (2048 * 512);
        d = dst + 9 * 262144 + 2 * (512 * 2048) + (size_t)l2 * (2048 * 512);
        K = 2048; N = 512; tn = tile & 7; tk = tile >> 3;
    }
    const int n0 = tn * 64, k0 = tk * 64;
    __shared__ float T[64][65];
    const int t = threadIdx.x;
    const int kl = t >> 4, n4 = (t & 15) << 2;
#pragma unroll
    for (int it = 0; it < 4; ++it) {
        const int k = kl + it * 16;
        float4 v = *(const float4*)(src + (size_t)(k0 + k) * N + n0 + n4);
        T[n4 + 0][k] = v.x; T[n4 + 1][k] = v.y;
        T[n4 + 2][k] = v.z; T[n4 + 3][k] = v.w;
    }
    __syncthreads();
    const int nl = t >> 3, k8 = (t & 7) << 3;
#pragma unroll
    for (int it = 0; it < 2; ++it) {
        const int n = nl + it * 32;
        ushort8 o;
#pragma unroll
        for (int c = 0; c < 8; ++c) o[c] = f2b(T[n][k8 + c]);
        *(ushort8*)(d + (size_t)(n0 + n) * K + k0 + k8) = o;
    }
}

// ---------------------------------------------------------------------------
// Flash-style monotonic attention v9: v8 structure (4-way j-split, LPT,
// dual-layer) + 32-BIT OFFSET ADDRESSING — kbase/vtb stay wave-uniform
// (SGPR) and all K/V loads use unsigned 32-bit offsets (saddr+voffset form;
// kills the per-lane v_lshl_add_u64 chains) — and sqrt via v_rsq_f32.
// ---------------------------------------------------------------------------
__global__ __launch_bounds__(256, 8) void attn_flash9(
    const unsigned short* __restrict__ Kb0, const unsigned short* __restrict__ Vt0,
    const unsigned short* __restrict__ Kb1, const unsigned short* __restrict__ Vt1,
    const float* __restrict__ gam,           // base; layer adds Hdim
    unsigned short* __restrict__ Ob0, unsigned short* __restrict__ Ob1,
    int mask_type, int dual)
{
    __shared__ float CTw[16 * 33];               // cross-tile strict suffix
    __shared__ unsigned short Pst[4][16 * 36];   // P staging (A-frag layout, per wave)
    __shared__ float S1s[4][16];                 // sum1 partials [w][row]
    __shared__ float S2s[4][16];                 // sum2 partials
    __shared__ float OaccA[16 * 66];             // oacc combine buffers
    __shared__ float OaccB[16 * 66];

    int bh, layer;
    if (dual) { layer = blockIdx.x & 1; bh = blockIdx.x >> 1; }
    else      { layer = 0;              bh = blockIdx.x; }
    const unsigned short* Kb = layer ? Kb1 : Kb0;
    const unsigned short* Vt = layer ? Vt1 : Vt0;
    unsigned short* Ob       = layer ? Ob1 : Ob0;
    const float* g           = gam + layer * Hdim;

    const int h = bh & 7, b = bh >> 3;
    const int rk = blockIdx.y;                   // LPT rank: 0 = heaviest
    const int tile = mask_type ? (31 - rk) : (rk == 0 ? 0 : 32 - rk);

    const int t = threadIdx.x, lane = t & 63, w = t >> 6;   // w: j-split slot
    const int quad = lane >> 4, fr = lane & 15;
    const int q0 = tile * 16;
    const int iRow = q0 + fr;                // this lane's q row

    const unsigned short* kbase = Kb + (size_t)b * Sdim * Ddim + h * DKdim;   // uniform
    const unsigned short* vtb = Vt + (size_t)(b * Hdim + h) * DKdim * Sdim;   // uniform
    const float gneg2 = -log1pf(__expf(g[h])) * 1.4426950408889634f;

    // 32-bit lane offsets (shorts); Ddim == Sdim == 512
    const unsigned lane_off = ((unsigned)fr << 9) + (unsigned)quad * 8;
    const unsigned kvstep = 16u * Ddim;      // 8192 shorts per jn-tile

    // Q as B-operand: rows q0+fr
    frag16 aq0 = *(const frag16*)(kbase + ((unsigned)q0 << 9) + lane_off);
    frag16 aq1 = *(const frag16*)(kbase + ((unsigned)q0 << 9) + lane_off + 32);

    // ---- Pass 1: sum1 partials + per-tile totals into CT (4-way jn split)
    float psum = 0.f;
    {
        unsigned ko = (unsigned)w * kvstep + lane_off;
        for (int jn = w; jn <= tile; jn += 4, ko += 4 * kvstep) {
            frag16 k0 = *(const frag16*)(kbase + ko);
            frag16 k1 = *(const frag16*)(kbase + ko + 32);
            f32x4 z = {0.f, 0.f, 0.f, 0.f};
            z = __builtin_amdgcn_mfma_f32_16x16x32_bf16(k0, aq0, z, 0, 0, 0);
            z = __builtin_amdgcn_mfma_f32_16x16x32_bf16(k1, aq1, z, 0, 0, 0);
            float tq = 0.f;
            if (jn < tile) {                 // fully-valid tile (both masks)
#pragma unroll
                for (int r = 0; r < 4; ++r) tq += EXP2(z[r] * SC2);
            } else {                         // diagonal tile
#pragma unroll
                for (int r = 0; r < 4; ++r) {
                    const bool valid = mask_type ? (quad * 4 + r <= fr)
                                                 : (quad * 4 + r < fr);
                    tq += valid ? EXP2(z[r] * SC2) : 0.f;
                }
            }
            psum += tq;
            float tt = tq;
            tt += __shfl_xor(tt, 16);
            tt += __shfl_xor(tt, 32);
            if (quad == 0) CTw[fr * 33 + jn] = tt;
        }
    }
    {
        float s1 = psum;
        s1 += __shfl_xor(s1, 16);
        s1 += __shfl_xor(s1, 32);
        if (lane < 16) S1s[w][lane] = s1;
    }
    __syncthreads();

    // totals -> strict cross-tile suffix (wave 0; rows by lanes 0..15)
    if (w == 0 && lane < 16) {
        float run = 0.f;
        for (int jn = tile; jn >= 0; --jn) {
            const float tv = CTw[lane * 33 + jn];
            CTw[lane * 33 + jn] = run;
            run += tv;
        }
    }
    __syncthreads();

    const float rsum1 = 1.f / (S1s[0][fr] + S1s[1][fr] + S1s[2][fr] + S1s[3][fr]);
    unsigned short* Pw = Pst[w];
    const bool fm_blk = (mask_type == 0) && (tile == 0);
    const bool fmrow = fm_blk && (fr == 0);
    const int umax = fm_blk ? (Sdim / 32 - 1) : (tile >> 1);
    float sum2p = 0.f;
    f32x4 oacc[4] = {};

    // ---- Pass 2: independent u-tiles, 4-way split, online PV
    for (int u = umax - w; u >= 0; u -= 4) {
        const unsigned ko2 = ((unsigned)u << 14) + lane_off;   // (2u)*8192
#pragma unroll
        for (int half = 0; half < 2; ++half) {
            const int jn = 2 * u + half;
            uint2 pku;
            if (jn > tile) {
                // empty tile: P=0, except mask0 row-0 uniform case (P=1)
                const unsigned int pv = fmrow ? 0x3F803F80u : 0u;
                pku.x = pv; pku.y = pv;
                sum2p += fmrow ? 4.f : 0.f;
            } else {
                const unsigned koh = ko2 + (unsigned)half * kvstep;
                frag16 k0 = *(const frag16*)(kbase + koh);
                frag16 k1 = *(const frag16*)(kbase + koh + 32);
                f32x4 z = {0.f, 0.f, 0.f, 0.f};
                z = __builtin_amdgcn_mfma_f32_16x16x32_bf16(k0, aq0, z, 0, 0, 0);
                z = __builtin_amdgcn_mfma_f32_16x16x32_bf16(k1, aq1, z, 0, 0, 0);
                const bool full = (jn < tile);   // wave-uniform
                float s2r[4], lsuf[4];
                float tq = 0.f;
#pragma unroll
                for (int r = 3; r >= 0; --r) {
                    lsuf[r] = tq;                // strict suffix within 4-run
                    s2r[r] = z[r] * SC2;
                    float e1 = EXP2(s2r[r]);
                    if (!full) {
                        const bool valid = mask_type ? (quad * 4 + r <= fr)
                                                     : (quad * 4 + r < fr);
                        e1 = valid ? e1 : 0.f;
                    }
                    tq += e1;
                }
                // strict suffix over quads (2 guarded shfl_down)
                float incl = tq;
                {
                    float u1 = __shfl_down(incl, 16);
                    incl += (quad < 3) ? u1 : 0.f;
                    float u2 = __shfl_down(incl, 32);
                    incl += (quad < 2) ? u2 : 0.f;
                }
                const float base = CTw[fr * 33 + jn] + (incl - tq);
                const float pos0 = (float)(iRow - (jn * 16 + quad * 4));
                float e2v[4];
#pragma unroll
                for (int r = 0; r < 4; ++r) {
                    const float ratio = (base + lsuf[r]) * rsum1;   // >= 0
                    const float arg = ratio * fabsf(pos0 - (float)r);
                    // sqrt via v_rsq: NaN-safe at arg==0
                    const float sq = arg * rsqrtf(fmaxf(arg, 1e-30f));
                    const float te = fmaxf(EXP2(gneg2 * sq), 1e-5f); // <= 1
                    float e2 = EXP2(s2r[r] * te);
                    if (!full) {
                        const bool valid = mask_type ? (quad * 4 + r <= fr)
                                                     : (quad * 4 + r < fr);
                        e2 = valid ? e2 : (fmrow ? 1.f : 0.f);
                    }
                    sum2p += e2;
                    e2v[r] = e2;
                }
                union { __hip_bfloat162 hh; unsigned int u; } c0, c1;
                c0.hh = __float22bfloat162_rn(make_float2(e2v[0], e2v[1]));
                c1.hh = __float22bfloat162_rn(make_float2(e2v[2], e2v[3]));
                pku.x = c0.u; pku.y = c1.u;
            }
            *(uint2*)(Pw + fr * 36 + half * 16 + quad * 4) = pku;
        }
        // PV over this pair's 32-wide window (A = P from LDS, B = Vt)
        frag16 pf = *(const frag16*)(Pw + fr * 36 + quad * 8);
        const unsigned vo = lane_off + ((unsigned)u << 5);   // fr*512 + quad*8 + u*32
#pragma unroll
        for (int dt = 0; dt < 4; ++dt) {
            frag16 vf = *(const frag16*)(vtb + vo + (unsigned)dt * 8192u);
            oacc[dt] = __builtin_amdgcn_mfma_f32_16x16x32_bf16(pf, vf, oacc[dt], 0, 0, 0);
        }
    }

    // ---- combine the four waves' partials (2-step tree through 2 buffers)
    {
        float s2 = sum2p;
        s2 += __shfl_xor(s2, 16);
        s2 += __shfl_xor(s2, 32);
        if (lane < 16) S2s[w][lane] = s2;
    }
    if (w == 1) {
#pragma unroll
        for (int dt = 0; dt < 4; ++dt)
#pragma unroll
            for (int r = 0; r < 4; ++r)
                OaccA[(quad * 4 + r) * 66 + dt * 16 + fr] = oacc[dt][r];
    }
    if (w == 3) {
#pragma unroll
        for (int dt = 0; dt < 4; ++dt)
#pragma unroll
            for (int r = 0; r < 4; ++r)
                OaccB[(quad * 4 + r) * 66 + dt * 16 + fr] = oacc[dt][r];
    }
    __syncthreads();
    if (w == 0) {
#pragma unroll
        for (int dt = 0; dt < 4; ++dt)
#pragma unroll
            for (int r = 0; r < 4; ++r)
                oacc[dt][r] += OaccA[(quad * 4 + r) * 66 + dt * 16 + fr];
    }
    if (w == 2) {
#pragma unroll
        for (int dt = 0; dt < 4; ++dt)
#pragma unroll
            for (int r = 0; r < 4; ++r)
                oacc[dt][r] += OaccB[(quad * 4 + r) * 66 + dt * 16 + fr];
    }
    __syncthreads();
    if (w == 2) {
#pragma unroll
        for (int dt = 0; dt < 4; ++dt)
#pragma unroll
            for (int r = 0; r < 4; ++r)
                OaccA[(quad * 4 + r) * 66 + dt * 16 + fr] = oacc[dt][r];
    }
    __syncthreads();

    if (w == 0) {
        const float rs2 = 1.f / (S2s[0][fr] + S2s[1][fr] + S2s[2][fr] + S2s[3][fr]);
        float rs2q[4];
#pragma unroll
        for (int r = 0; r < 4; ++r) rs2q[r] = __shfl(rs2, quad * 4 + r);

        // O rows q0+quad*4+r, cols dt*16+fr
        unsigned short* obase = Ob + ((size_t)(b * Sdim + q0)) * Ddim + h * DKdim;
#pragma unroll
        for (int dt = 0; dt < 4; ++dt)
#pragma unroll
            for (int r = 0; r < 4; ++r) {
                const float v = oacc[dt][r] + OaccA[(quad * 4 + r) * 66 + dt * 16 + fr];
                obase[(size_t)(quad * 4 + r) * Ddim + dt * 16 + fr] = f2b(v * rs2q[r]);
            }
    }
}

// ---------------------------------------------------------------------------
// LayerNorm, WAVE-PER-ROW (no barriers): 64 lanes x 8 f32, 12 shfl_xor.
// Optional fp32 partial P fused-added to X (split-K combine). fp32 out
// (nullable) + bf16 out (nullable). 4 rows per 256-thread block.
// ---------------------------------------------------------------------------
__device__ __forceinline__ void ln_row_wave(
    const float* __restrict__ X, const float* __restrict__ P,
    const float* __restrict__ g, const float* __restrict__ bta,
    float* __restrict__ Y, unsigned short* __restrict__ Yb,
    int row, int lane)
{
    const size_t base = (size_t)row * Ddim + lane * 8;
    float4 a = *(const float4*)(X + base);
    float4 b = *(const float4*)(X + base + 4);
    if (P) {
        float4 pa = *(const float4*)(P + base);
        float4 pb = *(const float4*)(P + base + 4);
        a.x += pa.x; a.y += pa.y; a.z += pa.z; a.w += pa.w;
        b.x += pb.x; b.y += pb.y; b.z += pb.z; b.w += pb.w;
    }
    float s  = a.x + a.y + a.z + a.w + b.x + b.y + b.z + b.w;
    float s2 = a.x * a.x + a.y * a.y + a.z * a.z + a.w * a.w
             + b.x * b.x + b.y * b.y + b.z * b.z + b.w * b.w;
#pragma unroll
    for (int off = 1; off < 64; off <<= 1) {
        s  += __shfl_xor(s, off);
        s2 += __shfl_xor(s2, off);
    }
    const float mean = s * (1.f / Ddim);
    const float var = s2 * (1.f / Ddim) - mean * mean;
    const float rs = rsqrtf(var + 1e-5f);
    float4 ga = *(const float4*)(g + lane * 8);
    float4 gb = *(const float4*)(g + lane * 8 + 4);
    float4 ba = *(const float4*)(bta + lane * 8);
    float4 bb = *(const float4*)(bta + lane * 8 + 4);
    float y[8];
    y[0] = (a.x - mean) * rs * ga.x + ba.x;
    y[1] = (a.y - mean) * rs * ga.y + ba.y;
    y[2] = (a.z - mean) * rs * ga.z + ba.z;
    y[3] = (a.w - mean) * rs * ga.w + ba.w;
    y[4] = (b.x - mean) * rs * gb.x + bb.x;
    y[5] = (b.y - mean) * rs * gb.y + bb.y;
    y[6] = (b.z - mean) * rs * gb.z + bb.z;
    y[7] = (b.w - mean) * rs * gb.w + bb.w;
    if (Y) {
        *(float4*)(Y + base)     = make_float4(y[0], y[1], y[2], y[3]);
        *(float4*)(Y + base + 4) = make_float4(y[4], y[5], y[6], y[7]);
    }
    if (Yb) {
        ushort8 o;
#pragma unroll
        for (int c = 0; c < 8; ++c) o[c] = f2b(y[c]);
        *(ushort8*)(Yb + base) = o;
    }
}

__global__ __launch_bounds__(256) void ln_w1(
    const float* __restrict__ X, const float* __restrict__ P,
    const float* __restrict__ g, const float* __restrict__ bta,
    float* __restrict__ Y, unsigned short* __restrict__ Yb)
{
    const int row = blockIdx.x * 4 + (threadIdx.x >> 6);
    ln_row_wave(X, P, g, bta, Y, Yb, row, threadIdx.x & 63);
}

// dual-tensor LN with per-set partials: rows [0,Mrows) set a, rest set b
__global__ __launch_bounds__(256) void ln_w2(
    const float* __restrict__ Xa, const float* __restrict__ Pa,
    const float* __restrict__ ga, const float* __restrict__ ba,
    float* __restrict__ Ya, unsigned short* __restrict__ Yba,
    const float* __restrict__ Xb, const float* __restrict__ Pb,
    const float* __restrict__ gb, const float* __restrict__ bb,
    float* __restrict__ Yb2, unsigned short* __restrict__ Ybb)
{
    const int row = blockIdx.x * 4 + (threadIdx.x >> 6);
    if (row < Mrows)
        ln_row_wave(Xa, Pa, ga, ba, Ya, Yba, row, threadIdx.x & 63);
    else
        ln_row_wave(Xb, Pb, gb, bb, Yb2, Ybb, row - Mrows, threadIdx.x & 63);
}

// ---------------------------------------------------------------------------
extern "C" void kernel_launch(void* const* d_in, const int* in_sizes, int n_in,
                              void* d_out, int out_size, void* d_ws, size_t ws_size,
                              hipStream_t stream)
{
    const float* x0     = (const float*)d_in[0];
    const float* y0     = (const float*)d_in[1];
    const float* Wk     = (const float*)d_in[2];
    const float* bk     = (const float*)d_in[3];
    const float* Wv     = (const float*)d_in[4];
    const float* bv     = (const float*)d_in[5];
    const float* Wo     = (const float*)d_in[6];
    const float* bo     = (const float*)d_in[7];
    const float* gammas = (const float*)d_in[8];
    const float* ln1g   = (const float*)d_in[9];
    const float* ln1b   = (const float*)d_in[10];
    const float* W1     = (const float*)d_in[11];
    const float* b1     = (const float*)d_in[12];
    const float* W2     = (const float*)d_in[13];
    const float* b2     = (const float*)d_in[14];
    const float* ln2g   = (const float*)d_in[15];
    const float* ln2b   = (const float*)d_in[16];

    const size_t NBSD = (size_t)Mrows * Ddim;   // 4,194,304
    float* ws = (float*)d_ws;
    float* T1   = ws;
    float* X1   = T1 + NBSD;
    float* Xbuf = X1 + NBSD;
    unsigned short* Kbf = (unsigned short*)(Xbuf + NBSD);
    unsigned short* Vt  = Kbf + NBSD;
    unsigned short* AOb = Vt + NBSD;
    unsigned short* Abf = AOb + NBSD;
    unsigned short* Xbf = Abf + NBSD;
    unsigned short* Ybf = Xbf + NBSD;
    unsigned short* Hbb = Ybf + NBSD;                       // [M,F] = 4 NBSD units
    unsigned short* WtAll = Hbb + (size_t)Mrows * Fdim;

    // transient aliases (all regions dead at their aliased use time):
    unsigned short* Xb_in = Hbb;                 // bf16(x0), consumed by kv4
    unsigned short* AOb1  = Hbb + NBSD;          // layer-1 attention out
    unsigned short* Yb_in = Hbb + 2 * NBSD;      // bf16(y0), consumed by kv4
    unsigned short* Kbf1  = Abf;                 // layer-1 K (dead until LN writes Abf)
    unsigned short* Vt1   = Ybf;                 // layer-1 Vt (dead until LN2_0 writes Ybf)
    float* T1b = (float*)d_out;                  // layer-1 O out (dead until final LN)
    float* P1  = (float*)AOb;                    // FFN2 split-K partial (AOb+Abf dead there)
    float* PO2 = (float*)Hbb;                    // O-proj l2 partial (Hbb dead at step 12-13)

    auto WtK = [&](int l) { return WtAll + (size_t)(l * 3 + 0) * 262144; };
    auto WtV = [&](int l) { return WtAll + (size_t)(l * 3 + 1) * 262144; };
    auto WtO = [&](int l) { return WtAll + (size_t)(l * 3 + 2) * 262144; };
    auto Wt1 = [&](int l) { return WtAll + 9 * 262144 + (size_t)(l >> 1) * (512 * 2048); };
    auto Wt2 = [&](int l) { return WtAll + 9 * 262144 + 2 * (512 * 2048) + (size_t)(l >> 1) * (2048 * 512); };

    const int convBlocks = (int)(NBSD / 2048);   // 2048

    // 1. weight transposes
    wtrans_all<<<1600, 256, 0, stream>>>(Wk, Wv, Wo, W1, W2, WtAll);
    // 2. both inputs -> bf16 (one launch)
    conv_b2<<<2 * convBlocks, 256, 0, stream>>>(y0, Yb_in, x0, Xb_in, convBlocks);
    // 3. KV projections for layers 0 and 1 (one launch, z=0..3)
    gemm_kv4<<<dim3(8, 64, 4), 256, 0, stream>>>(
        Yb_in, Xb_in, WtK(0), WtV(0), WtK(1), WtV(1),
        bk, bv, bk + Ddim, bv + Ddim,
        Kbf, Vt, Kbf1, Vt1);
    // 4. attention layers 0+1 merged (mask1 both; layer interleaved in x)
    attn_flash9<<<dim3(2 * Bdim * Hdim, Sdim / 16, 1), 256, 0, stream>>>(
        Kbf, Vt, Kbf1, Vt1, gammas, AOb, AOb1, 1, 1);
    // 5. O-projections + residual, split-K=2 (z = layer*2 + khalf)
    gemm_o2<<<dim3(8, 64, 4), 256, 0, stream>>>(
        AOb, AOb1, WtO(0), WtO(1), bo, bo + Ddim, y0, x0,
        T1, T1b, X1 /*P_l0*/, Xbuf /*P_l1*/);
    // 6. LN1 both layers (P-fused): L0 -> X1 + Abf; L1 -> Xbuf + Xbf (final)
    ln_w2<<<2 * Mrows / 4, 256, 0, stream>>>(
        T1, X1, ln1g, ln1b, X1, Abf,
        T1b, Xbuf, ln1g + Ddim, ln1b + Ddim, Xbuf, Xbf);
    // 7-9. block-0 FFN (FFN2 split-K=2, LN combines) + LN2 -> Ybf
    gemm_mfma<<<dim3(Fdim / 128, Mrows / 128), 256, 0, stream>>>(
        (const __hip_bfloat16*)Abf, (const __hip_bfloat16*)Wt1(0),
        b1, nullptr, nullptr, Hbb, Mrows, Fdim, Ddim, 1);
    gemm_splitk<<<dim3(8, 64, 2), 256, 0, stream>>>(
        Hbb, Wt2(0), b2, X1, T1, P1, 2048, 1024);
    ln_w1<<<Mrows / 4, 256, 0, stream>>>(T1, P1, ln2g, ln2b, nullptr, Ybf);

    // ---- block 2: knowledge retriever (q/k = x-out, v = y-out, mask0, FFN)
    const int l = 2;
    // 10. KV (dual z): K from Xbf, V from Ybf
    gemm_n64<<<dim3(8, 64, 2), 256, 0, stream>>>(
        Xbf, Ybf, WtK(l), WtV(l), bk + l * Ddim, bv + l * Ddim,
        nullptr, nullptr, Kbf, Vt, Ddim);
    // 11. attention (mask0, single layer)
    attn_flash9<<<dim3(Bdim * Hdim, Sdim / 16, 1), 256, 0, stream>>>(
        Kbf, Vt, Kbf, Vt, gammas + (size_t)l * Hdim, AOb, AOb, 0, 0);
    // 12. O-projection + residual (Xbuf), split-K=2
    gemm_splitk<<<dim3(8, 64, 2), 256, 0, stream>>>(
        AOb, WtO(l), bo + l * Ddim, Xbuf, T1, PO2, 512, 256);
    // 13. LN1 (P-fused) -> X1 + Abf
    ln_w1<<<Mrows / 4, 256, 0, stream>>>(T1, PO2,
        ln1g + (size_t)l * Ddim, ln1b + (size_t)l * Ddim, X1, Abf);
    // 14-16. FFN (split-K FFN2) + LN2 -> d_out (fp32)
    gemm_mfma<<<dim3(Fdim / 128, Mrows / 128), 256, 0, stream>>>(
        (const __hip_bfloat16*)Abf, (const __hip_bfloat16*)Wt1(l),
        b1 + (size_t)l * Fdim, nullptr, nullptr, Hbb, Mrows, Fdim, Ddim, 1);
    gemm_splitk<<<dim3(8, 64, 2), 256, 0, stream>>>(
        Hbb, Wt2(l), b2 + (size_t)l * Ddim, X1, T1, P1, 2048, 1024);
    ln_w1<<<Mrows / 4, 256, 0, stream>>>(T1, P1,
        ln2g + (size_t)l * Ddim, ln2b + (size_t)l * Ddim, (float*)d_out, nullptr);
}

// Round 12
// 552.015 us; speedup vs baseline: 1.0322x; 1.0322x over previous
//
#include <hip/hip_runtime.h>
#include <hip/hip_bf16.h>

// Problem dims (fixed)
#define Bdim 16
#define Sdim 512
#define Ddim 512
#define Hdim 8
#define DKdim 64
#define Fdim 2048
#define Mrows (Bdim * Sdim)   // 8192

typedef __attribute__((ext_vector_type(8))) short  frag16;   // 8 bf16 (4 VGPRs)
typedef __attribute__((ext_vector_type(4))) float  f32x4;    // MFMA acc
typedef __attribute__((ext_vector_type(8))) unsigned short ushort8;
typedef __attribute__((ext_vector_type(4))) unsigned short ushort4v;

// raw 2^x (v_exp_f32); fallback keeps semantics
#if defined(__has_builtin)
#  if __has_builtin(__builtin_amdgcn_exp2f)
#    define EXP2(x) __builtin_amdgcn_exp2f(x)
#  endif
#endif
#ifndef EXP2
#  define EXP2(x) __expf((x) * 0.6931471805599453f)
#endif
#define SC2 0.18033688011112042f   // 0.125 * log2(e)

// round-to-nearest-even fp32 -> bf16 (finite data)
__device__ __forceinline__ unsigned short f2b(float x) {
    union { float f; unsigned int u; } v; v.f = x;
    unsigned int r = (v.u + 0x7FFFu + ((v.u >> 16) & 1u)) >> 16;
    return (unsigned short)r;
}

// ---------------------------------------------------------------------------
// bf16 MFMA GEMM, 128x128 tile (used for FFN1, N=2048).
// XCD-chunked swizzle + 2-phase double-buffered K-loop.
// ---------------------------------------------------------------------------
__global__ __launch_bounds__(256) void gemm_mfma(
    const __hip_bfloat16* __restrict__ A, const __hip_bfloat16* __restrict__ Bt,
    const float* __restrict__ bias, const float* __restrict__ R,
    float* __restrict__ Cf, unsigned short* __restrict__ Cb,
    int M, int N, int K, int do_relu)
{
    __shared__ short As[2][128 * 32];
    __shared__ short Bs[2][128 * 32];

    const int t = threadIdx.x;
    const int lane = t & 63;
    const int wave = t >> 6;

    // XCD-aware chunked swizzle (grid size divisible by 8)
    const int gx = gridDim.x;
    const int nb = gx * gridDim.y;
    const int lid = blockIdx.x + gx * blockIdx.y;
    const int wid = (lid & 7) * (nb >> 3) + (lid >> 3);
    const int bm = (wid / gx) * 128;
    const int bn = (wid % gx) * 128;

    const int wm = (wave >> 1) * 64;
    const int wn = (wave & 1) * 64;

    f32x4 acc[4][4] = {};
    const int lrow = lane >> 2;
    const int lcol = (lane & 3) * 8;

    auto stage = [&](int k0, int buf) {
#pragma unroll
        for (int i = 0; i < 2; ++i) {
            const int chunk = wave * 2 + i;
            const int row = chunk * 16 + lrow;
            const __hip_bfloat16* ga = A + (size_t)(bm + row) * K + k0 + lcol;
            const __hip_bfloat16* gb = Bt + (size_t)(bn + row) * K + k0 + lcol;
            __builtin_amdgcn_global_load_lds(
                (const __attribute__((address_space(1))) unsigned int*)ga,
                (__attribute__((address_space(3))) unsigned int*)(&As[buf][chunk * 512]),
                16, 0, 0);
            __builtin_amdgcn_global_load_lds(
                (const __attribute__((address_space(1))) unsigned int*)gb,
                (__attribute__((address_space(3))) unsigned int*)(&Bs[buf][chunk * 512]),
                16, 0, 0);
        }
    };

    const int fr = lane & 15;
    const int quad = lane >> 4;
    const int nk = K >> 5;

    stage(0, 0);
    __syncthreads();

    for (int it = 0; it < nk; ++it) {
        const int buf = it & 1;
        if (it + 1 < nk) stage((it + 1) << 5, buf ^ 1);
        frag16 af[4], bfr[4];
#pragma unroll
        for (int i = 0; i < 4; ++i) {
            af[i]  = *(const frag16*)(&As[buf][(wm + i * 16 + fr) * 32 + quad * 8]);
            bfr[i] = *(const frag16*)(&Bs[buf][(wn + i * 16 + fr) * 32 + quad * 8]);
        }
#pragma unroll
        for (int mi = 0; mi < 4; ++mi)
#pragma unroll
            for (int ni = 0; ni < 4; ++ni)
                acc[mi][ni] = __builtin_amdgcn_mfma_f32_16x16x32_bf16(
                    af[mi], bfr[ni], acc[mi][ni], 0, 0, 0);
        __syncthreads();
    }

#pragma unroll
    for (int mi = 0; mi < 4; ++mi) {
#pragma unroll
        for (int r = 0; r < 4; ++r) {
            const int m = bm + wm + mi * 16 + quad * 4 + r;
#pragma unroll
            for (int ni = 0; ni < 4; ++ni) {
                const int n = bn + wn + ni * 16 + fr;
                float v = acc[mi][ni][r] + bias[n];
                if (R) v += R[(size_t)m * N + n];
                if (do_relu) v = fmaxf(v, 0.f);
                if (Cf) Cf[(size_t)m * N + n] = v;
                if (Cb) Cb[(size_t)m * N + n] = f2b(v);
            }
        }
    }
}

// ---------------------------------------------------------------------------
// bf16 MFMA GEMM, 128x64 tile, N=512 fixed, BK=64 (16 MFMA per barrier).
// XOR-swizzled LDS (source pre-swizzle + read-side XOR). Dual-mode via z:
// z=0: A0@B0^T+bias0 -> Cb / Cf(+R);  z=1: A1@B1^T+bias1 -> CbT (Vt layout)
// ---------------------------------------------------------------------------
__global__ __launch_bounds__(256) void gemm_n64(
    const unsigned short* __restrict__ A0, const unsigned short* __restrict__ A1,
    const unsigned short* __restrict__ B0, const unsigned short* __restrict__ B1,
    const float* __restrict__ bias0, const float* __restrict__ bias1,
    const float* __restrict__ R, float* __restrict__ Cf,
    unsigned short* __restrict__ Cb, unsigned short* __restrict__ CbT,
    int K)
{
    const int NN = 512;
    __shared__ short As[2][128 * 64];   // 32 KB
    __shared__ short Bs[2][64 * 64];    // 16 KB

    const int trans = blockIdx.z;
    const unsigned short* A  = trans ? A1 : A0;
    const unsigned short* Bt = trans ? B1 : B0;
    const float* bias        = trans ? bias1 : bias0;

    const int t = threadIdx.x;
    const int lane = t & 63;
    const int wave = t >> 6;

    const int lid = blockIdx.x + 8 * blockIdx.y;          // 0..511
    const int wid = (lid & 7) * 64 + (lid >> 3);
    const int bm = (wid >> 3) * 128;
    const int bn = (wid & 7) * 64;

    const int wm = (wave >> 1) * 64;
    const int wn = (wave & 1) * 32;

    f32x4 acc[4][2] = {};

    const int srcslot = (((lane & 7) ^ (lane >> 3)) << 3);
    const int rsub = lane >> 3;

    auto stage = [&](int k0, int buf) {
#pragma unroll
        for (int i = 0; i < 4; ++i) {
            const int row = i * 32 + wave * 8 + rsub;
            const unsigned short* ga = A + (size_t)(bm + row) * K + k0 + srcslot;
            __builtin_amdgcn_global_load_lds(
                (const __attribute__((address_space(1))) unsigned int*)ga,
                (__attribute__((address_space(3))) unsigned int*)(&As[buf][(i * 256 + wave * 64) * 8]),
                16, 0, 0);
        }
#pragma unroll
        for (int i = 0; i < 2; ++i) {
            const int row = i * 32 + wave * 8 + rsub;
            const unsigned short* gb = Bt + (size_t)(bn + row) * K + k0 + srcslot;
            __builtin_amdgcn_global_load_lds(
                (const __attribute__((address_space(1))) unsigned int*)gb,
                (__attribute__((address_space(3))) unsigned int*)(&Bs[buf][(i * 256 + wave * 64) * 8]),
                16, 0, 0);
        }
    };

    const int fr = lane & 15;
    const int quad = lane >> 4;
    const int sw = (fr & 7) << 3;
    const int nk = K >> 6;

    stage(0, 0);
    __syncthreads();

    for (int it = 0; it < nk; ++it) {
        const int buf = it & 1;
        if (it + 1 < nk) stage((it + 1) << 6, buf ^ 1);
        frag16 af[2][4], bfr[2][2];
#pragma unroll
        for (int ks = 0; ks < 2; ++ks) {
            const int col = (ks * 32 + quad * 8) ^ sw;
#pragma unroll
            for (int i = 0; i < 4; ++i)
                af[ks][i] = *(const frag16*)(&As[buf][(wm + i * 16 + fr) * 64 + col]);
#pragma unroll
            for (int i = 0; i < 2; ++i)
                bfr[ks][i] = *(const frag16*)(&Bs[buf][(wn + i * 16 + fr) * 64 + col]);
        }
#pragma unroll
        for (int ks = 0; ks < 2; ++ks)
#pragma unroll
            for (int mi = 0; mi < 4; ++mi)
#pragma unroll
                for (int ni = 0; ni < 2; ++ni)
                    acc[mi][ni] = __builtin_amdgcn_mfma_f32_16x16x32_bf16(
                        af[ks][mi], bfr[ks][ni], acc[mi][ni], 0, 0, 0);
        __syncthreads();
    }

    if (trans) {
#pragma unroll
        for (int mi = 0; mi < 4; ++mi)
#pragma unroll
            for (int ni = 0; ni < 2; ++ni) {
                const int m = bm + wm + mi * 16 + quad * 4;
                const int n = bn + wn + ni * 16 + fr;
                ushort4v o;
#pragma unroll
                for (int r = 0; r < 4; ++r) o[r] = f2b(acc[mi][ni][r] + bias[n]);
                const int bb = m >> 9, s = m & 511;
                const int hh = n >> 6, dd = n & 63;
                *(ushort4v*)(CbT + (((size_t)((bb * Hdim + hh) * DKdim + dd)) << 9) + s) = o;
            }
        return;
    }

#pragma unroll
    for (int mi = 0; mi < 4; ++mi) {
#pragma unroll
        for (int r = 0; r < 4; ++r) {
            const int m = bm + wm + mi * 16 + quad * 4 + r;
#pragma unroll
            for (int ni = 0; ni < 2; ++ni) {
                const int n = bn + wn + ni * 16 + fr;
                float v = acc[mi][ni][r] + bias[n];
                if (R) v += R[(size_t)m * NN + n];
                if (Cf) Cf[(size_t)m * NN + n] = v;
                if (Cb) Cb[(size_t)m * NN + n] = f2b(v);
            }
        }
    }
}

// ---------------------------------------------------------------------------
// Generic SPLIT-K=2 GEMM, 128x64 tile, N=512 fixed, fp32 out. (FFN2 only —
// pays at K=2048/nk=16; measured regression at K=512/nk=4, don't use there.)
// z=0: K in [0,KH)   -> C0 = acc + bias + R
// z=1: K in [KH,2KH) -> C1 = acc   (raw partial; following LN fuses C0+C1)
// ---------------------------------------------------------------------------
__global__ __launch_bounds__(256) void gemm_splitk(
    const unsigned short* __restrict__ A, const unsigned short* __restrict__ Bt,
    const float* __restrict__ bias, const float* __restrict__ R,
    float* __restrict__ C0, float* __restrict__ C1,
    int K, int KH)
{
    __shared__ short As[2][128 * 64];
    __shared__ short Bs[2][64 * 64];

    const int z = blockIdx.z;
    const int kb0 = z * KH;

    const int t = threadIdx.x;
    const int lane = t & 63;
    const int wave = t >> 6;

    const int lid = blockIdx.x + 8 * blockIdx.y;
    const int wid = (lid & 7) * 64 + (lid >> 3);
    const int bm = (wid >> 3) * 128;
    const int bn = (wid & 7) * 64;

    const int wm = (wave >> 1) * 64;
    const int wn = (wave & 1) * 32;

    f32x4 acc[4][2] = {};
    const int srcslot = (((lane & 7) ^ (lane >> 3)) << 3);
    const int rsub = lane >> 3;

    auto stage = [&](int k0, int buf) {
#pragma unroll
        for (int i = 0; i < 4; ++i) {
            const int row = i * 32 + wave * 8 + rsub;
            const unsigned short* ga = A + (size_t)(bm + row) * K + k0 + srcslot;
            __builtin_amdgcn_global_load_lds(
                (const __attribute__((address_space(1))) unsigned int*)ga,
                (__attribute__((address_space(3))) unsigned int*)(&As[buf][(i * 256 + wave * 64) * 8]),
                16, 0, 0);
        }
#pragma unroll
        for (int i = 0; i < 2; ++i) {
            const int row = i * 32 + wave * 8 + rsub;
            const unsigned short* gb = Bt + (size_t)(bn + row) * K + k0 + srcslot;
            __builtin_amdgcn_global_load_lds(
                (const __attribute__((address_space(1))) unsigned int*)gb,
                (__attribute__((address_space(3))) unsigned int*)(&Bs[buf][(i * 256 + wave * 64) * 8]),
                16, 0, 0);
        }
    };

    const int fr = lane & 15;
    const int quad = lane >> 4;
    const int sw = (fr & 7) << 3;
    const int nk = KH >> 6;

    stage(kb0, 0);
    __syncthreads();

    for (int it = 0; it < nk; ++it) {
        const int buf = it & 1;
        if (it + 1 < nk) stage(kb0 + ((it + 1) << 6), buf ^ 1);
        frag16 af[2][4], bfr[2][2];
#pragma unroll
        for (int ks = 0; ks < 2; ++ks) {
            const int col = (ks * 32 + quad * 8) ^ sw;
#pragma unroll
            for (int i = 0; i < 4; ++i)
                af[ks][i] = *(const frag16*)(&As[buf][(wm + i * 16 + fr) * 64 + col]);
#pragma unroll
            for (int i = 0; i < 2; ++i)
                bfr[ks][i] = *(const frag16*)(&Bs[buf][(wn + i * 16 + fr) * 64 + col]);
        }
#pragma unroll
        for (int ks = 0; ks < 2; ++ks)
#pragma unroll
            for (int mi = 0; mi < 4; ++mi)
#pragma unroll
                for (int ni = 0; ni < 2; ++ni)
                    acc[mi][ni] = __builtin_amdgcn_mfma_f32_16x16x32_bf16(
                        af[ks][mi], bfr[ks][ni], acc[mi][ni], 0, 0, 0);
        __syncthreads();
    }

#pragma unroll
    for (int mi = 0; mi < 4; ++mi) {
#pragma unroll
        for (int r = 0; r < 4; ++r) {
            const int m = bm + wm + mi * 16 + quad * 4 + r;
#pragma unroll
            for (int ni = 0; ni < 2; ++ni) {
                const int n = bn + wn + ni * 16 + fr;
                if (z == 0)
                    C0[(size_t)m * 512 + n] = acc[mi][ni][r] + bias[n] + R[(size_t)m * 512 + n];
                else
                    C1[(size_t)m * 512 + n] = acc[mi][ni][r];
            }
        }
    }
}

// ---------------------------------------------------------------------------
// 4-way KV projection: z in 0..3 selects {L0-K, L0-V(trans), L1-K, L1-V(trans)}.
// Same verified BK=64 swizzled core as gemm_n64; K fixed at 512.
// ---------------------------------------------------------------------------
__global__ __launch_bounds__(256) void gemm_kv4(
    const unsigned short* __restrict__ Ya, const unsigned short* __restrict__ Xa,
    const unsigned short* __restrict__ BtK0, const unsigned short* __restrict__ BtV0,
    const unsigned short* __restrict__ BtK1, const unsigned short* __restrict__ BtV1,
    const float* __restrict__ bk0, const float* __restrict__ bv0,
    const float* __restrict__ bk1, const float* __restrict__ bv1,
    unsigned short* __restrict__ K0, unsigned short* __restrict__ V0t,
    unsigned short* __restrict__ K1, unsigned short* __restrict__ V1t)
{
    const int K = 512;
    __shared__ short As[2][128 * 64];
    __shared__ short Bs[2][64 * 64];

    const int z = blockIdx.z;
    const unsigned short* A  = (z < 2) ? Ya : Xa;
    const unsigned short* Bt = (z == 0) ? BtK0 : (z == 1) ? BtV0 : (z == 2) ? BtK1 : BtV1;
    const float* bias        = (z == 0) ? bk0 : (z == 1) ? bv0 : (z == 2) ? bk1 : bv1;
    const int trans = z & 1;

    const int t = threadIdx.x;
    const int lane = t & 63;
    const int wave = t >> 6;

    const int lid = blockIdx.x + 8 * blockIdx.y;
    const int wid = (lid & 7) * 64 + (lid >> 3);
    const int bm = (wid >> 3) * 128;
    const int bn = (wid & 7) * 64;

    const int wm = (wave >> 1) * 64;
    const int wn = (wave & 1) * 32;

    f32x4 acc[4][2] = {};
    const int srcslot = (((lane & 7) ^ (lane >> 3)) << 3);
    const int rsub = lane >> 3;

    auto stage = [&](int k0, int buf) {
#pragma unroll
        for (int i = 0; i < 4; ++i) {
            const int row = i * 32 + wave * 8 + rsub;
            const unsigned short* ga = A + (size_t)(bm + row) * K + k0 + srcslot;
            __builtin_amdgcn_global_load_lds(
                (const __attribute__((address_space(1))) unsigned int*)ga,
                (__attribute__((address_space(3))) unsigned int*)(&As[buf][(i * 256 + wave * 64) * 8]),
                16, 0, 0);
        }
#pragma unroll
        for (int i = 0; i < 2; ++i) {
            const int row = i * 32 + wave * 8 + rsub;
            const unsigned short* gb = Bt + (size_t)(bn + row) * K + k0 + srcslot;
            __builtin_amdgcn_global_load_lds(
                (const __attribute__((address_space(1))) unsigned int*)gb,
                (__attribute__((address_space(3))) unsigned int*)(&Bs[buf][(i * 256 + wave * 64) * 8]),
                16, 0, 0);
        }
    };

    const int fr = lane & 15;
    const int quad = lane >> 4;
    const int sw = (fr & 7) << 3;
    const int nk = K >> 6;

    stage(0, 0);
    __syncthreads();

    for (int it = 0; it < nk; ++it) {
        const int buf = it & 1;
        if (it + 1 < nk) stage((it + 1) << 6, buf ^ 1);
        frag16 af[2][4], bfr[2][2];
#pragma unroll
        for (int ks = 0; ks < 2; ++ks) {
            const int col = (ks * 32 + quad * 8) ^ sw;
#pragma unroll
            for (int i = 0; i < 4; ++i)
                af[ks][i] = *(const frag16*)(&As[buf][(wm + i * 16 + fr) * 64 + col]);
#pragma unroll
            for (int i = 0; i < 2; ++i)
                bfr[ks][i] = *(const frag16*)(&Bs[buf][(wn + i * 16 + fr) * 64 + col]);
        }
#pragma unroll
        for (int ks = 0; ks < 2; ++ks)
#pragma unroll
            for (int mi = 0; mi < 4; ++mi)
#pragma unroll
                for (int ni = 0; ni < 2; ++ni)
                    acc[mi][ni] = __builtin_amdgcn_mfma_f32_16x16x32_bf16(
                        af[ks][mi], bfr[ks][ni], acc[mi][ni], 0, 0, 0);
        __syncthreads();
    }

    if (trans) {
        unsigned short* CbT = (z == 1) ? V0t : V1t;
#pragma unroll
        for (int mi = 0; mi < 4; ++mi)
#pragma unroll
            for (int ni = 0; ni < 2; ++ni) {
                const int m = bm + wm + mi * 16 + quad * 4;
                const int n = bn + wn + ni * 16 + fr;
                ushort4v o;
#pragma unroll
                for (int r = 0; r < 4; ++r) o[r] = f2b(acc[mi][ni][r] + bias[n]);
                const int bb = m >> 9, s = m & 511;
                const int hh = n >> 6, dd = n & 63;
                *(ushort4v*)(CbT + (((size_t)((bb * Hdim + hh) * DKdim + dd)) << 9) + s) = o;
            }
    } else {
        unsigned short* Cb = (z == 0) ? K0 : K1;
#pragma unroll
        for (int mi = 0; mi < 4; ++mi)
#pragma unroll
            for (int r = 0; r < 4; ++r) {
                const int m = bm + wm + mi * 16 + quad * 4 + r;
#pragma unroll
                for (int ni = 0; ni < 2; ++ni) {
                    const int n = bn + wn + ni * 16 + fr;
                    Cb[(size_t)m * 512 + n] = f2b(acc[mi][ni][r] + bias[n]);
                }
            }
    }
}

// ---------------------------------------------------------------------------
// Dual O-projection (FULL-K, round-9 proven): z in {0,1} selects layer;
// C = A@Bt + bias + R (fp32). Same verified BK=64 swizzled core. K=512.
// ---------------------------------------------------------------------------
__global__ __launch_bounds__(256) void gemm_o2(
    const unsigned short* __restrict__ A0, const unsigned short* __restrict__ A1,
    const unsigned short* __restrict__ B0, const unsigned short* __restrict__ B1,
    const float* __restrict__ bias0, const float* __restrict__ bias1,
    const float* __restrict__ R0, const float* __restrict__ R1,
    float* __restrict__ C0, float* __restrict__ C1)
{
    const int K = 512;
    __shared__ short As[2][128 * 64];
    __shared__ short Bs[2][64 * 64];

    const int z = blockIdx.z;
    const unsigned short* A  = z ? A1 : A0;
    const unsigned short* Bt = z ? B1 : B0;
    const float* bias        = z ? bias1 : bias0;
    const float* R           = z ? R1 : R0;
    float* Cf                = z ? C1 : C0;

    const int t = threadIdx.x;
    const int lane = t & 63;
    const int wave = t >> 6;

    const int lid = blockIdx.x + 8 * blockIdx.y;
    const int wid = (lid & 7) * 64 + (lid >> 3);
    const int bm = (wid >> 3) * 128;
    const int bn = (wid & 7) * 64;

    const int wm = (wave >> 1) * 64;
    const int wn = (wave & 1) * 32;

    f32x4 acc[4][2] = {};
    const int srcslot = (((lane & 7) ^ (lane >> 3)) << 3);
    const int rsub = lane >> 3;

    auto stage = [&](int k0, int buf) {
#pragma unroll
        for (int i = 0; i < 4; ++i) {
            const int row = i * 32 + wave * 8 + rsub;
            const unsigned short* ga = A + (size_t)(bm + row) * K + k0 + srcslot;
            __builtin_amdgcn_global_load_lds(
                (const __attribute__((address_space(1))) unsigned int*)ga,
                (__attribute__((address_space(3))) unsigned int*)(&As[buf][(i * 256 + wave * 64) * 8]),
                16, 0, 0);
        }
#pragma unroll
        for (int i = 0; i < 2; ++i) {
            const int row = i * 32 + wave * 8 + rsub;
            const unsigned short* gb = Bt + (size_t)(bn + row) * K + k0 + srcslot;
            __builtin_amdgcn_global_load_lds(
                (const __attribute__((address_space(1))) unsigned int*)gb,
                (__attribute__((address_space(3))) unsigned int*)(&Bs[buf][(i * 256 + wave * 64) * 8]),
                16, 0, 0);
        }
    };

    const int fr = lane & 15;
    const int quad = lane >> 4;
    const int sw = (fr & 7) << 3;
    const int nk = K >> 6;

    stage(0, 0);
    __syncthreads();

    for (int it = 0; it < nk; ++it) {
        const int buf = it & 1;
        if (it + 1 < nk) stage((it + 1) << 6, buf ^ 1);
        frag16 af[2][4], bfr[2][2];
#pragma unroll
        for (int ks = 0; ks < 2; ++ks) {
            const int col = (ks * 32 + quad * 8) ^ sw;
#pragma unroll
            for (int i = 0; i < 4; ++i)
                af[ks][i] = *(const frag16*)(&As[buf][(wm + i * 16 + fr) * 64 + col]);
#pragma unroll
            for (int i = 0; i < 2; ++i)
                bfr[ks][i] = *(const frag16*)(&Bs[buf][(wn + i * 16 + fr) * 64 + col]);
        }
#pragma unroll
        for (int ks = 0; ks < 2; ++ks)
#pragma unroll
            for (int mi = 0; mi < 4; ++mi)
#pragma unroll
                for (int ni = 0; ni < 2; ++ni)
                    acc[mi][ni] = __builtin_amdgcn_mfma_f32_16x16x32_bf16(
                        af[ks][mi], bfr[ks][ni], acc[mi][ni], 0, 0, 0);
        __syncthreads();
    }

#pragma unroll
    for (int mi = 0; mi < 4; ++mi) {
#pragma unroll
        for (int r = 0; r < 4; ++r) {
            const int m = bm + wm + mi * 16 + quad * 4 + r;
#pragma unroll
            for (int ni = 0; ni < 2; ++ni) {
                const int n = bn + wn + ni * 16 + fr;
                Cf[(size_t)m * 512 + n] = acc[mi][ni][r] + bias[n] + R[(size_t)m * 512 + n];
            }
        }
    }
}

// ---------------------------------------------------------------------------
// fp32 -> bf16 convert, dual-source (two tensors in one launch)
// ---------------------------------------------------------------------------
__global__ __launch_bounds__(256) void conv_b2(
    const float* __restrict__ X0, unsigned short* __restrict__ Y0,
    const float* __restrict__ X1, unsigned short* __restrict__ Y1,
    int halfBlocks)
{
    const int bid = blockIdx.x;
    const float* X = (bid < halfBlocks) ? X0 : X1;
    unsigned short* Y = (bid < halfBlocks) ? Y0 : Y1;
    const int lb = (bid < halfBlocks) ? bid : bid - halfBlocks;
    const size_t i = ((size_t)lb * 256 + threadIdx.x) * 8;
    float4 a = *(const float4*)(X + i);
    float4 b = *(const float4*)(X + i + 4);
    ushort8 o;
    o[0] = f2b(a.x); o[1] = f2b(a.y); o[2] = f2b(a.z); o[3] = f2b(a.w);
    o[4] = f2b(b.x); o[5] = f2b(b.y); o[6] = f2b(b.z); o[7] = f2b(b.w);
    *(ushort8*)(Y + i) = o;
}

// ---------------------------------------------------------------------------
// ALL weight transposes fused: 1600 tiles of 64x64, [K,N] fp32 -> [N,K] bf16
// ---------------------------------------------------------------------------
__global__ __launch_bounds__(256) void wtrans_all(
    const float* __restrict__ Wk, const float* __restrict__ Wv,
    const float* __restrict__ Wo, const float* __restrict__ W1,
    const float* __restrict__ W2, unsigned short* __restrict__ dst)
{
    const int bid = blockIdx.x;
    const float* src; unsigned short* d; int K, N, tk, tn;
    if (bid < 576) {
        const int mat = bid >> 6, tile = bid & 63;
        const int l = mat / 3, wch = mat % 3;
        const float* W = (wch == 0) ? Wk : (wch == 1) ? Wv : Wo;
        src = W + (size_t)l * 262144;
        d = dst + (size_t)mat * 262144;
        K = 512; N = 512; tn = tile & 7; tk = tile >> 3;
    } else if (bid < 1088) {
        const int idx = bid - 576, l2 = idx >> 8, tile = idx & 255;
        src = W1 + (size_t)(l2 * 2) * (512 * 2048);
        d = dst + 9 * 262144 + (size_t)l2 * (512 * 2048);
        K = 512; N = 2048; tn = tile & 31; tk = tile >> 5;
    } else {
        const int idx = bid - 1088, l2 = idx >> 8, tile = idx & 255;
        src = W2 + (size_t)(l2 * 2) * (2048 * 512);
        d = dst + 9 * 262144 + 2 * (512 * 2048) + (size_t)l2 * (2048 * 512);
        K = 2048; N = 512; tn = tile & 7; tk = tile >> 3;
    }
    const int n0 = tn * 64, k0 = tk * 64;
    __shared__ float T[64][65];
    const int t = threadIdx.x;
    const int kl = t >> 4, n4 = (t & 15) << 2;
#pragma unroll
    for (int it = 0; it < 4; ++it) {
        const int k = kl + it * 16;
        float4 v = *(const float4*)(src + (size_t)(k0 + k) * N + n0 + n4);
        T[n4 + 0][k] = v.x; T[n4 + 1][k] = v.y;
        T[n4 + 2][k] = v.z; T[n4 + 3][k] = v.w;
    }
    __syncthreads();
    const int nl = t >> 3, k8 = (t & 7) << 3;
#pragma unroll
    for (int it = 0; it < 2; ++it) {
        const int n = nl + it * 32;
        ushort8 o;
#pragma unroll
        for (int c = 0; c < 8; ++c) o[c] = f2b(T[n][k8 + c]);
        *(ushort8*)(d + (size_t)(n0 + n) * K + k0 + k8) = o;
    }
}

// ---------------------------------------------------------------------------
// Flash-style monotonic attention v9: v8 structure (4-way j-split, LPT,
// dual-layer) + 32-BIT OFFSET ADDRESSING — kbase/vtb stay wave-uniform
// (SGPR) and all K/V loads use unsigned 32-bit offsets (saddr+voffset form)
// — and sqrt via v_rsq_f32.
// ---------------------------------------------------------------------------
__global__ __launch_bounds__(256, 8) void attn_flash9(
    const unsigned short* __restrict__ Kb0, const unsigned short* __restrict__ Vt0,
    const unsigned short* __restrict__ Kb1, const unsigned short* __restrict__ Vt1,
    const float* __restrict__ gam,           // base; layer adds Hdim
    unsigned short* __restrict__ Ob0, unsigned short* __restrict__ Ob1,
    int mask_type, int dual)
{
    __shared__ float CTw[16 * 33];               // cross-tile strict suffix
    __shared__ unsigned short Pst[4][16 * 36];   // P staging (A-frag layout, per wave)
    __shared__ float S1s[4][16];                 // sum1 partials [w][row]
    __shared__ float S2s[4][16];                 // sum2 partials
    __shared__ float OaccA[16 * 66];             // oacc combine buffers
    __shared__ float OaccB[16 * 66];

    int bh, layer;
    if (dual) { layer = blockIdx.x & 1; bh = blockIdx.x >> 1; }
    else      { layer = 0;              bh = blockIdx.x; }
    const unsigned short* Kb = layer ? Kb1 : Kb0;
    const unsigned short* Vt = layer ? Vt1 : Vt0;
    unsigned short* Ob       = layer ? Ob1 : Ob0;
    const float* g           = gam + layer * Hdim;

    const int h = bh & 7, b = bh >> 3;
    const int rk = blockIdx.y;                   // LPT rank: 0 = heaviest
    const int tile = mask_type ? (31 - rk) : (rk == 0 ? 0 : 32 - rk);

    const int t = threadIdx.x, lane = t & 63, w = t >> 6;   // w: j-split slot
    const int quad = lane >> 4, fr = lane & 15;
    const int q0 = tile * 16;
    const int iRow = q0 + fr;                // this lane's q row

    const unsigned short* kbase = Kb + (size_t)b * Sdim * Ddim + h * DKdim;   // uniform
    const unsigned short* vtb = Vt + (size_t)(b * Hdim + h) * DKdim * Sdim;   // uniform
    const float gneg2 = -log1pf(__expf(g[h])) * 1.4426950408889634f;

    // 32-bit lane offsets (shorts); Ddim == Sdim == 512
    const unsigned lane_off = ((unsigned)fr << 9) + (unsigned)quad * 8;
    const unsigned kvstep = 16u * Ddim;      // 8192 shorts per jn-tile

    // Q as B-operand: rows q0+fr
    frag16 aq0 = *(const frag16*)(kbase + ((unsigned)q0 << 9) + lane_off);
    frag16 aq1 = *(const frag16*)(kbase + ((unsigned)q0 << 9) + lane_off + 32);

    // ---- Pass 1: sum1 partials + per-tile totals into CT (4-way jn split)
    float psum = 0.f;
    {
        unsigned ko = (unsigned)w * kvstep + lane_off;
        for (int jn = w; jn <= tile; jn += 4, ko += 4 * kvstep) {
            frag16 k0 = *(const frag16*)(kbase + ko);
            frag16 k1 = *(const frag16*)(kbase + ko + 32);
            f32x4 z = {0.f, 0.f, 0.f, 0.f};
            z = __builtin_amdgcn_mfma_f32_16x16x32_bf16(k0, aq0, z, 0, 0, 0);
            z = __builtin_amdgcn_mfma_f32_16x16x32_bf16(k1, aq1, z, 0, 0, 0);
            float tq = 0.f;
            if (jn < tile) {                 // fully-valid tile (both masks)
#pragma unroll
                for (int r = 0; r < 4; ++r) tq += EXP2(z[r] * SC2);
            } else {                         // diagonal tile
#pragma unroll
                for (int r = 0; r < 4; ++r) {
                    const bool valid = mask_type ? (quad * 4 + r <= fr)
                                                 : (quad * 4 + r < fr);
                    tq += valid ? EXP2(z[r] * SC2) : 0.f;
                }
            }
            psum += tq;
            float tt = tq;
            tt += __shfl_xor(tt, 16);
            tt += __shfl_xor(tt, 32);
            if (quad == 0) CTw[fr * 33 + jn] = tt;
        }
    }
    {
        float s1 = psum;
        s1 += __shfl_xor(s1, 16);
        s1 += __shfl_xor(s1, 32);
        if (lane < 16) S1s[w][lane] = s1;
    }
    __syncthreads();

    // totals -> strict cross-tile suffix (wave 0; rows by lanes 0..15)
    if (w == 0 && lane < 16) {
        float run = 0.f;
        for (int jn = tile; jn >= 0; --jn) {
            const float tv = CTw[lane * 33 + jn];
            CTw[lane * 33 + jn] = run;
            run += tv;
        }
    }
    __syncthreads();

    const float rsum1 = 1.f / (S1s[0][fr] + S1s[1][fr] + S1s[2][fr] + S1s[3][fr]);
    unsigned short* Pw = Pst[w];
    const bool fm_blk = (mask_type == 0) && (tile == 0);
    const bool fmrow = fm_blk && (fr == 0);
    const int umax = fm_blk ? (Sdim / 32 - 1) : (tile >> 1);
    float sum2p = 0.f;
    f32x4 oacc[4] = {};

    // ---- Pass 2: independent u-tiles, 4-way split, online PV
    for (int u = umax - w; u >= 0; u -= 4) {
        const unsigned ko2 = ((unsigned)u << 14) + lane_off;   // (2u)*8192
#pragma unroll
        for (int half = 0; half < 2; ++half) {
            const int jn = 2 * u + half;
            uint2 pku;
            if (jn > tile) {
                // empty tile: P=0, except mask0 row-0 uniform case (P=1)
                const unsigned int pv = fmrow ? 0x3F803F80u : 0u;
                pku.x = pv; pku.y = pv;
                sum2p += fmrow ? 4.f : 0.f;
            } else {
                const unsigned koh = ko2 + (unsigned)half * kvstep;
                frag16 k0 = *(const frag16*)(kbase + koh);
                frag16 k1 = *(const frag16*)(kbase + koh + 32);
                f32x4 z = {0.f, 0.f, 0.f, 0.f};
                z = __builtin_amdgcn_mfma_f32_16x16x32_bf16(k0, aq0, z, 0, 0, 0);
                z = __builtin_amdgcn_mfma_f32_16x16x32_bf16(k1, aq1, z, 0, 0, 0);
                const bool full = (jn < tile);   // wave-uniform
                float s2r[4], lsuf[4];
                float tq = 0.f;
#pragma unroll
                for (int r = 3; r >= 0; --r) {
                    lsuf[r] = tq;                // strict suffix within 4-run
                    s2r[r] = z[r] * SC2;
                    float e1 = EXP2(s2r[r]);
                    if (!full) {
                        const bool valid = mask_type ? (quad * 4 + r <= fr)
                                                     : (quad * 4 + r < fr);
                        e1 = valid ? e1 : 0.f;
                    }
                    tq += e1;
                }
                // strict suffix over quads (2 guarded shfl_down)
                float incl = tq;
                {
                    float u1 = __shfl_down(incl, 16);
                    incl += (quad < 3) ? u1 : 0.f;
                    float u2 = __shfl_down(incl, 32);
                    incl += (quad < 2) ? u2 : 0.f;
                }
                const float base = CTw[fr * 33 + jn] + (incl - tq);
                const float pos0 = (float)(iRow - (jn * 16 + quad * 4));
                float e2v[4];
#pragma unroll
                for (int r = 0; r < 4; ++r) {
                    const float ratio = (base + lsuf[r]) * rsum1;   // >= 0
                    const float arg = ratio * fabsf(pos0 - (float)r);
                    // sqrt via v_rsq: NaN-safe at arg==0
                    const float sq = arg * rsqrtf(fmaxf(arg, 1e-30f));
                    const float te = fmaxf(EXP2(gneg2 * sq), 1e-5f); // <= 1
                    float e2 = EXP2(s2r[r] * te);
                    if (!full) {
                        const bool valid = mask_type ? (quad * 4 + r <= fr)
                                                     : (quad * 4 + r < fr);
                        e2 = valid ? e2 : (fmrow ? 1.f : 0.f);
                    }
                    sum2p += e2;
                    e2v[r] = e2;
                }
                union { __hip_bfloat162 hh; unsigned int u; } c0, c1;
                c0.hh = __float22bfloat162_rn(make_float2(e2v[0], e2v[1]));
                c1.hh = __float22bfloat162_rn(make_float2(e2v[2], e2v[3]));
                pku.x = c0.u; pku.y = c1.u;
            }
            *(uint2*)(Pw + fr * 36 + half * 16 + quad * 4) = pku;
        }
        // PV over this pair's 32-wide window (A = P from LDS, B = Vt)
        frag16 pf = *(const frag16*)(Pw + fr * 36 + quad * 8);
        const unsigned vo = lane_off + ((unsigned)u << 5);   // fr*512 + quad*8 + u*32
#pragma unroll
        for (int dt = 0; dt < 4; ++dt) {
            frag16 vf = *(const frag16*)(vtb + vo + (unsigned)dt * 8192u);
            oacc[dt] = __builtin_amdgcn_mfma_f32_16x16x32_bf16(pf, vf, oacc[dt], 0, 0, 0);
        }
    }

    // ---- combine the four waves' partials (2-step tree through 2 buffers)
    {
        float s2 = sum2p;
        s2 += __shfl_xor(s2, 16);
        s2 += __shfl_xor(s2, 32);
        if (lane < 16) S2s[w][lane] = s2;
    }
    if (w == 1) {
#pragma unroll
        for (int dt = 0; dt < 4; ++dt)
#pragma unroll
            for (int r = 0; r < 4; ++r)
                OaccA[(quad * 4 + r) * 66 + dt * 16 + fr] = oacc[dt][r];
    }
    if (w == 3) {
#pragma unroll
        for (int dt = 0; dt < 4; ++dt)
#pragma unroll
            for (int r = 0; r < 4; ++r)
                OaccB[(quad * 4 + r) * 66 + dt * 16 + fr] = oacc[dt][r];
    }
    __syncthreads();
    if (w == 0) {
#pragma unroll
        for (int dt = 0; dt < 4; ++dt)
#pragma unroll
            for (int r = 0; r < 4; ++r)
                oacc[dt][r] += OaccA[(quad * 4 + r) * 66 + dt * 16 + fr];
    }
    if (w == 2) {
#pragma unroll
        for (int dt = 0; dt < 4; ++dt)
#pragma unroll
            for (int r = 0; r < 4; ++r)
                oacc[dt][r] += OaccB[(quad * 4 + r) * 66 + dt * 16 + fr];
    }
    __syncthreads();
    if (w == 2) {
#pragma unroll
        for (int dt = 0; dt < 4; ++dt)
#pragma unroll
            for (int r = 0; r < 4; ++r)
                OaccA[(quad * 4 + r) * 66 + dt * 16 + fr] = oacc[dt][r];
    }
    __syncthreads();

    if (w == 0) {
        const float rs2 = 1.f / (S2s[0][fr] + S2s[1][fr] + S2s[2][fr] + S2s[3][fr]);
        float rs2q[4];
#pragma unroll
        for (int r = 0; r < 4; ++r) rs2q[r] = __shfl(rs2, quad * 4 + r);

        // O rows q0+quad*4+r, cols dt*16+fr
        unsigned short* obase = Ob + ((size_t)(b * Sdim + q0)) * Ddim + h * DKdim;
#pragma unroll
        for (int dt = 0; dt < 4; ++dt)
#pragma unroll
            for (int r = 0; r < 4; ++r) {
                const float v = oacc[dt][r] + OaccA[(quad * 4 + r) * 66 + dt * 16 + fr];
                obase[(size_t)(quad * 4 + r) * Ddim + dt * 16 + fr] = f2b(v * rs2q[r]);
            }
    }
}

// ---------------------------------------------------------------------------
// LayerNorm, WAVE-PER-ROW (no barriers): 64 lanes x 8 f32, 12 shfl_xor.
// Optional fp32 partial P fused-added to X (split-K combine). fp32 out
// (nullable) + bf16 out (nullable). 4 rows per 256-thread block.
// ---------------------------------------------------------------------------
__device__ __forceinline__ void ln_row_wave(
    const float* __restrict__ X, const float* __restrict__ P,
    const float* __restrict__ g, const float* __restrict__ bta,
    float* __restrict__ Y, unsigned short* __restrict__ Yb,
    int row, int lane)
{
    const size_t base = (size_t)row * Ddim + lane * 8;
    float4 a = *(const float4*)(X + base);
    float4 b = *(const float4*)(X + base + 4);
    if (P) {
        float4 pa = *(const float4*)(P + base);
        float4 pb = *(const float4*)(P + base + 4);
        a.x += pa.x; a.y += pa.y; a.z += pa.z; a.w += pa.w;
        b.x += pb.x; b.y += pb.y; b.z += pb.z; b.w += pb.w;
    }
    float s  = a.x + a.y + a.z + a.w + b.x + b.y + b.z + b.w;
    float s2 = a.x * a.x + a.y * a.y + a.z * a.z + a.w * a.w
             + b.x * b.x + b.y * b.y + b.z * b.z + b.w * b.w;
#pragma unroll
    for (int off = 1; off < 64; off <<= 1) {
        s  += __shfl_xor(s, off);
        s2 += __shfl_xor(s2, off);
    }
    const float mean = s * (1.f / Ddim);
    const float var = s2 * (1.f / Ddim) - mean * mean;
    const float rs = rsqrtf(var + 1e-5f);
    float4 ga = *(const float4*)(g + lane * 8);
    float4 gb = *(const float4*)(g + lane * 8 + 4);
    float4 ba = *(const float4*)(bta + lane * 8);
    float4 bb = *(const float4*)(bta + lane * 8 + 4);
    float y[8];
    y[0] = (a.x - mean) * rs * ga.x + ba.x;
    y[1] = (a.y - mean) * rs * ga.y + ba.y;
    y[2] = (a.z - mean) * rs * ga.z + ba.z;
    y[3] = (a.w - mean) * rs * ga.w + ba.w;
    y[4] = (b.x - mean) * rs * gb.x + bb.x;
    y[5] = (b.y - mean) * rs * gb.y + bb.y;
    y[6] = (b.z - mean) * rs * gb.z + bb.z;
    y[7] = (b.w - mean) * rs * gb.w + bb.w;
    if (Y) {
        *(float4*)(Y + base)     = make_float4(y[0], y[1], y[2], y[3]);
        *(float4*)(Y + base + 4) = make_float4(y[4], y[5], y[6], y[7]);
    }
    if (Yb) {
        ushort8 o;
#pragma unroll
        for (int c = 0; c < 8; ++c) o[c] = f2b(y[c]);
        *(ushort8*)(Yb + base) = o;
    }
}

__global__ __launch_bounds__(256) void ln_w1(
    const float* __restrict__ X, const float* __restrict__ P,
    const float* __restrict__ g, const float* __restrict__ bta,
    float* __restrict__ Y, unsigned short* __restrict__ Yb)
{
    const int row = blockIdx.x * 4 + (threadIdx.x >> 6);
    ln_row_wave(X, P, g, bta, Y, Yb, row, threadIdx.x & 63);
}

// dual-tensor LN (no partials): rows [0,Mrows) set a, rest set b
__global__ __launch_bounds__(256) void ln_w2(
    const float* __restrict__ Xa, const float* __restrict__ ga,
    const float* __restrict__ ba, float* __restrict__ Ya,
    unsigned short* __restrict__ Yba,
    const float* __restrict__ Xb, const float* __restrict__ gb,
    const float* __restrict__ bb, float* __restrict__ Yb2,
    unsigned short* __restrict__ Ybb)
{
    const int row = blockIdx.x * 4 + (threadIdx.x >> 6);
    if (row < Mrows)
        ln_row_wave(Xa, nullptr, ga, ba, Ya, Yba, row, threadIdx.x & 63);
    else
        ln_row_wave(Xb, nullptr, gb, bb, Yb2, Ybb, row - Mrows, threadIdx.x & 63);
}

// ---------------------------------------------------------------------------
extern "C" void kernel_launch(void* const* d_in, const int* in_sizes, int n_in,
                              void* d_out, int out_size, void* d_ws, size_t ws_size,
                              hipStream_t stream)
{
    const float* x0     = (const float*)d_in[0];
    const float* y0     = (const float*)d_in[1];
    const float* Wk     = (const float*)d_in[2];
    const float* bk     = (const float*)d_in[3];
    const float* Wv     = (const float*)d_in[4];
    const float* bv     = (const float*)d_in[5];
    const float* Wo     = (const float*)d_in[6];
    const float* bo     = (const float*)d_in[7];
    const float* gammas = (const float*)d_in[8];
    const float* ln1g   = (const float*)d_in[9];
    const float* ln1b   = (const float*)d_in[10];
    const float* W1     = (const float*)d_in[11];
    const float* b1     = (const float*)d_in[12];
    const float* W2     = (const float*)d_in[13];
    const float* b2     = (const float*)d_in[14];
    const float* ln2g   = (const float*)d_in[15];
    const float* ln2b   = (const float*)d_in[16];

    const size_t NBSD = (size_t)Mrows * Ddim;   // 4,194,304
    float* ws = (float*)d_ws;
    float* T1   = ws;
    float* X1   = T1 + NBSD;
    float* Xbuf = X1 + NBSD;
    unsigned short* Kbf = (unsigned short*)(Xbuf + NBSD);
    unsigned short* Vt  = Kbf + NBSD;
    unsigned short* AOb = Vt + NBSD;
    unsigned short* Abf = AOb + NBSD;
    unsigned short* Xbf = Abf + NBSD;
    unsigned short* Ybf = Xbf + NBSD;
    unsigned short* Hbb = Ybf + NBSD;                       // [M,F] = 4 NBSD units
    unsigned short* WtAll = Hbb + (size_t)Mrows * Fdim;

    // transient aliases (all regions dead at their aliased use time):
    unsigned short* Xb_in = Hbb;                 // bf16(x0), consumed by kv4
    unsigned short* AOb1  = Hbb + NBSD;          // layer-1 attention out
    unsigned short* Yb_in = Hbb + 2 * NBSD;      // bf16(y0), consumed by kv4
    unsigned short* Kbf1  = Abf;                 // layer-1 K (dead until LN writes Abf)
    unsigned short* Vt1   = Ybf;                 // layer-1 Vt (dead until LN2_0 writes Ybf)
    float* T1b = (float*)d_out;                  // layer-1 O out (dead until final LN)
    float* P1  = (float*)AOb;                    // FFN2 split-K partial (AOb+Abf dead there)

    auto WtK = [&](int l) { return WtAll + (size_t)(l * 3 + 0) * 262144; };
    auto WtV = [&](int l) { return WtAll + (size_t)(l * 3 + 1) * 262144; };
    auto WtO = [&](int l) { return WtAll + (size_t)(l * 3 + 2) * 262144; };
    auto Wt1 = [&](int l) { return WtAll + 9 * 262144 + (size_t)(l >> 1) * (512 * 2048); };
    auto Wt2 = [&](int l) { return WtAll + 9 * 262144 + 2 * (512 * 2048) + (size_t)(l >> 1) * (2048 * 512); };

    const int convBlocks = (int)(NBSD / 2048);   // 2048

    // 1. weight transposes
    wtrans_all<<<1600, 256, 0, stream>>>(Wk, Wv, Wo, W1, W2, WtAll);
    // 2. both inputs -> bf16 (one launch)
    conv_b2<<<2 * convBlocks, 256, 0, stream>>>(y0, Yb_in, x0, Xb_in, convBlocks);
    // 3. KV projections for layers 0 and 1 (one launch, z=0..3)
    gemm_kv4<<<dim3(8, 64, 4), 256, 0, stream>>>(
        Yb_in, Xb_in, WtK(0), WtV(0), WtK(1), WtV(1),
        bk, bv, bk + Ddim, bv + Ddim,
        Kbf, Vt, Kbf1, Vt1);
    // 4. attention layers 0+1 merged (mask1 both; layer interleaved in x)
    attn_flash9<<<dim3(2 * Bdim * Hdim, Sdim / 16, 1), 256, 0, stream>>>(
        Kbf, Vt, Kbf1, Vt1, gammas, AOb, AOb1, 1, 1);
    // 5. O-projections + residual for layers 0+1 (one launch, full-K)
    gemm_o2<<<dim3(8, 64, 2), 256, 0, stream>>>(
        AOb, AOb1, WtO(0), WtO(1), bo, bo + Ddim, y0, x0, T1, T1b);
    // 6. LN1 for both layers: L0 -> X1 + Abf; L1 -> Xbuf + Xbf (final)
    ln_w2<<<2 * Mrows / 4, 256, 0, stream>>>(
        T1, ln1g, ln1b, X1, Abf,
        T1b, ln1g + Ddim, ln1b + Ddim, Xbuf, Xbf);
    // 7-9. block-0 FFN (FFN2 split-K=2, LN combines) + LN2 -> Ybf
    gemm_mfma<<<dim3(Fdim / 128, Mrows / 128), 256, 0, stream>>>(
        (const __hip_bfloat16*)Abf, (const __hip_bfloat16*)Wt1(0),
        b1, nullptr, nullptr, Hbb, Mrows, Fdim, Ddim, 1);
    gemm_splitk<<<dim3(8, 64, 2), 256, 0, stream>>>(
        Hbb, Wt2(0), b2, X1, T1, P1, 2048, 1024);
    ln_w1<<<Mrows / 4, 256, 0, stream>>>(T1, P1, ln2g, ln2b, nullptr, Ybf);

    // ---- block 2: knowledge retriever (q/k = x-out, v = y-out, mask0, FFN)
    const int l = 2;
    // 10. KV (dual z): K from Xbf, V from Ybf
    gemm_n64<<<dim3(8, 64, 2), 256, 0, stream>>>(
        Xbf, Ybf, WtK(l), WtV(l), bk + l * Ddim, bv + l * Ddim,
        nullptr, nullptr, Kbf, Vt, Ddim);
    // 11. attention (mask0, single layer)
    attn_flash9<<<dim3(Bdim * Hdim, Sdim / 16, 1), 256, 0, stream>>>(
        Kbf, Vt, Kbf, Vt, gammas + (size_t)l * Hdim, AOb, AOb, 0, 0);
    // 12. O-projection + residual (Xbuf), full-K
    gemm_n64<<<dim3(8, 64, 1), 256, 0, stream>>>(
        AOb, AOb, WtO(l), WtO(l), bo + l * Ddim, bo + l * Ddim,
        Xbuf, T1, nullptr, nullptr, Ddim);
    // 13. LN1 -> X1 + Abf
    ln_w1<<<Mrows / 4, 256, 0, stream>>>(T1, nullptr,
        ln1g + (size_t)l * Ddim, ln1b + (size_t)l * Ddim, X1, Abf);
    // 14-16. FFN (split-K FFN2) + LN2 -> d_out (fp32)
    gemm_mfma<<<dim3(Fdim / 128, Mrows / 128), 256, 0, stream>>>(
        (const __hip_bfloat16*)Abf, (const __hip_bfloat16*)Wt1(l),
        b1 + (size_t)l * Fdim, nullptr, nullptr, Hbb, Mrows, Fdim, Ddim, 1);
    gemm_splitk<<<dim3(8, 64, 2), 256, 0, stream>>>(
        Hbb, Wt2(l), b2 + (size_t)l * Ddim, X1, T1, P1, 2048, 1024);
    ln_w1<<<Mrows / 4, 256, 0, stream>>>(T1, P1,
        ln2g + (size_t)l * Ddim, ln2b + (size_t)l * Ddim, (float*)d_out, nullptr);
}

// Round 13
// 549.092 us; speedup vs baseline: 1.0377x; 1.0053x over previous
//
#include <hip/hip_runtime.h>
#include <hip/hip_bf16.h>

// Problem dims (fixed)
#define Bdim 16
#define Sdim 512
#define Ddim 512
#define Hdim 8
#define DKdim 64
#define Fdim 2048
#define Mrows (Bdim * Sdim)   // 8192

typedef __attribute__((ext_vector_type(8))) short  frag16;   // 8 bf16 (4 VGPRs)
typedef __attribute__((ext_vector_type(4))) float  f32x4;    // MFMA acc
typedef __attribute__((ext_vector_type(8))) unsigned short ushort8;
typedef __attribute__((ext_vector_type(4))) unsigned short ushort4v;

// raw 2^x (v_exp_f32); fallback keeps semantics
#if defined(__has_builtin)
#  if __has_builtin(__builtin_amdgcn_exp2f)
#    define EXP2(x) __builtin_amdgcn_exp2f(x)
#  endif
#endif
#ifndef EXP2
#  define EXP2(x) __expf((x) * 0.6931471805599453f)
#endif
#define SC2 0.18033688011112042f   // 0.125 * log2(e)

// round-to-nearest-even fp32 -> bf16 (finite data)
__device__ __forceinline__ unsigned short f2b(float x) {
    union { float f; unsigned int u; } v; v.f = x;
    unsigned int r = (v.u + 0x7FFFu + ((v.u >> 16) & 1u)) >> 16;
    return (unsigned short)r;
}

// ---------------------------------------------------------------------------
// bf16 MFMA GEMM, 128x128 tile (used for FFN1, N=2048).
// XCD-chunked swizzle + 2-phase double-buffered K-loop.
// ---------------------------------------------------------------------------
__global__ __launch_bounds__(256) void gemm_mfma(
    const __hip_bfloat16* __restrict__ A, const __hip_bfloat16* __restrict__ Bt,
    const float* __restrict__ bias, const float* __restrict__ R,
    float* __restrict__ Cf, unsigned short* __restrict__ Cb,
    int M, int N, int K, int do_relu)
{
    __shared__ short As[2][128 * 32];
    __shared__ short Bs[2][128 * 32];

    const int t = threadIdx.x;
    const int lane = t & 63;
    const int wave = t >> 6;

    // XCD-aware chunked swizzle (grid size divisible by 8)
    const int gx = gridDim.x;
    const int nb = gx * gridDim.y;
    const int lid = blockIdx.x + gx * blockIdx.y;
    const int wid = (lid & 7) * (nb >> 3) + (lid >> 3);
    const int bm = (wid / gx) * 128;
    const int bn = (wid % gx) * 128;

    const int wm = (wave >> 1) * 64;
    const int wn = (wave & 1) * 64;

    f32x4 acc[4][4] = {};
    const int lrow = lane >> 2;
    const int lcol = (lane & 3) * 8;

    auto stage = [&](int k0, int buf) {
#pragma unroll
        for (int i = 0; i < 2; ++i) {
            const int chunk = wave * 2 + i;
            const int row = chunk * 16 + lrow;
            const __hip_bfloat16* ga = A + (size_t)(bm + row) * K + k0 + lcol;
            const __hip_bfloat16* gb = Bt + (size_t)(bn + row) * K + k0 + lcol;
            __builtin_amdgcn_global_load_lds(
                (const __attribute__((address_space(1))) unsigned int*)ga,
                (__attribute__((address_space(3))) unsigned int*)(&As[buf][chunk * 512]),
                16, 0, 0);
            __builtin_amdgcn_global_load_lds(
                (const __attribute__((address_space(1))) unsigned int*)gb,
                (__attribute__((address_space(3))) unsigned int*)(&Bs[buf][chunk * 512]),
                16, 0, 0);
        }
    };

    const int fr = lane & 15;
    const int quad = lane >> 4;
    const int nk = K >> 5;

    stage(0, 0);
    __syncthreads();

    for (int it = 0; it < nk; ++it) {
        const int buf = it & 1;
        if (it + 1 < nk) stage((it + 1) << 5, buf ^ 1);
        frag16 af[4], bfr[4];
#pragma unroll
        for (int i = 0; i < 4; ++i) {
            af[i]  = *(const frag16*)(&As[buf][(wm + i * 16 + fr) * 32 + quad * 8]);
            bfr[i] = *(const frag16*)(&Bs[buf][(wn + i * 16 + fr) * 32 + quad * 8]);
        }
#pragma unroll
        for (int mi = 0; mi < 4; ++mi)
#pragma unroll
            for (int ni = 0; ni < 4; ++ni)
                acc[mi][ni] = __builtin_amdgcn_mfma_f32_16x16x32_bf16(
                    af[mi], bfr[ni], acc[mi][ni], 0, 0, 0);
        __syncthreads();
    }

#pragma unroll
    for (int mi = 0; mi < 4; ++mi) {
#pragma unroll
        for (int r = 0; r < 4; ++r) {
            const int m = bm + wm + mi * 16 + quad * 4 + r;
#pragma unroll
            for (int ni = 0; ni < 4; ++ni) {
                const int n = bn + wn + ni * 16 + fr;
                float v = acc[mi][ni][r] + bias[n];
                if (R) v += R[(size_t)m * N + n];
                if (do_relu) v = fmaxf(v, 0.f);
                if (Cf) Cf[(size_t)m * N + n] = v;
                if (Cb) Cb[(size_t)m * N + n] = f2b(v);
            }
        }
    }
}

// ---------------------------------------------------------------------------
// bf16 MFMA GEMM, 128x64 tile, N=512 fixed, BK=64 (16 MFMA per barrier).
// XOR-swizzled LDS (source pre-swizzle + read-side XOR). Dual-mode via z:
// z=0: A0@B0^T+bias0 -> Cb / Cf(+R);  z=1: A1@B1^T+bias1 -> CbT (Vt layout)
// ---------------------------------------------------------------------------
__global__ __launch_bounds__(256) void gemm_n64(
    const unsigned short* __restrict__ A0, const unsigned short* __restrict__ A1,
    const unsigned short* __restrict__ B0, const unsigned short* __restrict__ B1,
    const float* __restrict__ bias0, const float* __restrict__ bias1,
    const float* __restrict__ R, float* __restrict__ Cf,
    unsigned short* __restrict__ Cb, unsigned short* __restrict__ CbT,
    int K)
{
    const int NN = 512;
    __shared__ short As[2][128 * 64];   // 32 KB
    __shared__ short Bs[2][64 * 64];    // 16 KB

    const int trans = blockIdx.z;
    const unsigned short* A  = trans ? A1 : A0;
    const unsigned short* Bt = trans ? B1 : B0;
    const float* bias        = trans ? bias1 : bias0;

    const int t = threadIdx.x;
    const int lane = t & 63;
    const int wave = t >> 6;

    const int lid = blockIdx.x + 8 * blockIdx.y;          // 0..511
    const int wid = (lid & 7) * 64 + (lid >> 3);
    const int bm = (wid >> 3) * 128;
    const int bn = (wid & 7) * 64;

    const int wm = (wave >> 1) * 64;
    const int wn = (wave & 1) * 32;

    f32x4 acc[4][2] = {};

    const int srcslot = (((lane & 7) ^ (lane >> 3)) << 3);
    const int rsub = lane >> 3;

    auto stage = [&](int k0, int buf) {
#pragma unroll
        for (int i = 0; i < 4; ++i) {
            const int row = i * 32 + wave * 8 + rsub;
            const unsigned short* ga = A + (size_t)(bm + row) * K + k0 + srcslot;
            __builtin_amdgcn_global_load_lds(
                (const __attribute__((address_space(1))) unsigned int*)ga,
                (__attribute__((address_space(3))) unsigned int*)(&As[buf][(i * 256 + wave * 64) * 8]),
                16, 0, 0);
        }
#pragma unroll
        for (int i = 0; i < 2; ++i) {
            const int row = i * 32 + wave * 8 + rsub;
            const unsigned short* gb = Bt + (size_t)(bn + row) * K + k0 + srcslot;
            __builtin_amdgcn_global_load_lds(
                (const __attribute__((address_space(1))) unsigned int*)gb,
                (__attribute__((address_space(3))) unsigned int*)(&Bs[buf][(i * 256 + wave * 64) * 8]),
                16, 0, 0);
        }
    };

    const int fr = lane & 15;
    const int quad = lane >> 4;
    const int sw = (fr & 7) << 3;
    const int nk = K >> 6;

    stage(0, 0);
    __syncthreads();

    for (int it = 0; it < nk; ++it) {
        const int buf = it & 1;
        if (it + 1 < nk) stage((it + 1) << 6, buf ^ 1);
        frag16 af[2][4], bfr[2][2];
#pragma unroll
        for (int ks = 0; ks < 2; ++ks) {
            const int col = (ks * 32 + quad * 8) ^ sw;
#pragma unroll
            for (int i = 0; i < 4; ++i)
                af[ks][i] = *(const frag16*)(&As[buf][(wm + i * 16 + fr) * 64 + col]);
#pragma unroll
            for (int i = 0; i < 2; ++i)
                bfr[ks][i] = *(const frag16*)(&Bs[buf][(wn + i * 16 + fr) * 64 + col]);
        }
#pragma unroll
        for (int ks = 0; ks < 2; ++ks)
#pragma unroll
            for (int mi = 0; mi < 4; ++mi)
#pragma unroll
                for (int ni = 0; ni < 2; ++ni)
                    acc[mi][ni] = __builtin_amdgcn_mfma_f32_16x16x32_bf16(
                        af[ks][mi], bfr[ks][ni], acc[mi][ni], 0, 0, 0);
        __syncthreads();
    }

    if (trans) {
#pragma unroll
        for (int mi = 0; mi < 4; ++mi)
#pragma unroll
            for (int ni = 0; ni < 2; ++ni) {
                const int m = bm + wm + mi * 16 + quad * 4;
                const int n = bn + wn + ni * 16 + fr;
                ushort4v o;
#pragma unroll
                for (int r = 0; r < 4; ++r) o[r] = f2b(acc[mi][ni][r] + bias[n]);
                const int bb = m >> 9, s = m & 511;
                const int hh = n >> 6, dd = n & 63;
                *(ushort4v*)(CbT + (((size_t)((bb * Hdim + hh) * DKdim + dd)) << 9) + s) = o;
            }
        return;
    }

#pragma unroll
    for (int mi = 0; mi < 4; ++mi) {
#pragma unroll
        for (int r = 0; r < 4; ++r) {
            const int m = bm + wm + mi * 16 + quad * 4 + r;
#pragma unroll
            for (int ni = 0; ni < 2; ++ni) {
                const int n = bn + wn + ni * 16 + fr;
                float v = acc[mi][ni][r] + bias[n];
                if (R) v += R[(size_t)m * NN + n];
                if (Cf) Cf[(size_t)m * NN + n] = v;
                if (Cb) Cb[(size_t)m * NN + n] = f2b(v);
            }
        }
    }
}

// ---------------------------------------------------------------------------
// Generic SPLIT-K=2 GEMM, 128x64 tile, N=512 fixed, fp32 out. (FFN2 only —
// pays at K=2048/nk=16; measured regression at K=512/nk=4, don't use there.)
// z=0: K in [0,KH)   -> C0 = acc + bias + R
// z=1: K in [KH,2KH) -> C1 = acc   (raw partial; following LN fuses C0+C1)
// ---------------------------------------------------------------------------
__global__ __launch_bounds__(256) void gemm_splitk(
    const unsigned short* __restrict__ A, const unsigned short* __restrict__ Bt,
    const float* __restrict__ bias, const float* __restrict__ R,
    float* __restrict__ C0, float* __restrict__ C1,
    int K, int KH)
{
    __shared__ short As[2][128 * 64];
    __shared__ short Bs[2][64 * 64];

    const int z = blockIdx.z;
    const int kb0 = z * KH;

    const int t = threadIdx.x;
    const int lane = t & 63;
    const int wave = t >> 6;

    const int lid = blockIdx.x + 8 * blockIdx.y;
    const int wid = (lid & 7) * 64 + (lid >> 3);
    const int bm = (wid >> 3) * 128;
    const int bn = (wid & 7) * 64;

    const int wm = (wave >> 1) * 64;
    const int wn = (wave & 1) * 32;

    f32x4 acc[4][2] = {};
    const int srcslot = (((lane & 7) ^ (lane >> 3)) << 3);
    const int rsub = lane >> 3;

    auto stage = [&](int k0, int buf) {
#pragma unroll
        for (int i = 0; i < 4; ++i) {
            const int row = i * 32 + wave * 8 + rsub;
            const unsigned short* ga = A + (size_t)(bm + row) * K + k0 + srcslot;
            __builtin_amdgcn_global_load_lds(
                (const __attribute__((address_space(1))) unsigned int*)ga,
                (__attribute__((address_space(3))) unsigned int*)(&As[buf][(i * 256 + wave * 64) * 8]),
                16, 0, 0);
        }
#pragma unroll
        for (int i = 0; i < 2; ++i) {
            const int row = i * 32 + wave * 8 + rsub;
            const unsigned short* gb = Bt + (size_t)(bn + row) * K + k0 + srcslot;
            __builtin_amdgcn_global_load_lds(
                (const __attribute__((address_space(1))) unsigned int*)gb,
                (__attribute__((address_space(3))) unsigned int*)(&Bs[buf][(i * 256 + wave * 64) * 8]),
                16, 0, 0);
        }
    };

    const int fr = lane & 15;
    const int quad = lane >> 4;
    const int sw = (fr & 7) << 3;
    const int nk = KH >> 6;

    stage(kb0, 0);
    __syncthreads();

    for (int it = 0; it < nk; ++it) {
        const int buf = it & 1;
        if (it + 1 < nk) stage(kb0 + ((it + 1) << 6), buf ^ 1);
        frag16 af[2][4], bfr[2][2];
#pragma unroll
        for (int ks = 0; ks < 2; ++ks) {
            const int col = (ks * 32 + quad * 8) ^ sw;
#pragma unroll
            for (int i = 0; i < 4; ++i)
                af[ks][i] = *(const frag16*)(&As[buf][(wm + i * 16 + fr) * 64 + col]);
#pragma unroll
            for (int i = 0; i < 2; ++i)
                bfr[ks][i] = *(const frag16*)(&Bs[buf][(wn + i * 16 + fr) * 64 + col]);
        }
#pragma unroll
        for (int ks = 0; ks < 2; ++ks)
#pragma unroll
            for (int mi = 0; mi < 4; ++mi)
#pragma unroll
                for (int ni = 0; ni < 2; ++ni)
                    acc[mi][ni] = __builtin_amdgcn_mfma_f32_16x16x32_bf16(
                        af[ks][mi], bfr[ks][ni], acc[mi][ni], 0, 0, 0);
        __syncthreads();
    }

#pragma unroll
    for (int mi = 0; mi < 4; ++mi) {
#pragma unroll
        for (int r = 0; r < 4; ++r) {
            const int m = bm + wm + mi * 16 + quad * 4 + r;
#pragma unroll
            for (int ni = 0; ni < 2; ++ni) {
                const int n = bn + wn + ni * 16 + fr;
                if (z == 0)
                    C0[(size_t)m * 512 + n] = acc[mi][ni][r] + bias[n] + R[(size_t)m * 512 + n];
                else
                    C1[(size_t)m * 512 + n] = acc[mi][ni][r];
            }
        }
    }
}

// ---------------------------------------------------------------------------
// 4-way KV projection: z in 0..3 selects {L0-K, L0-V(trans), L1-K, L1-V(trans)}.
// Same verified BK=64 swizzled core as gemm_n64; K fixed at 512.
// ---------------------------------------------------------------------------
__global__ __launch_bounds__(256) void gemm_kv4(
    const unsigned short* __restrict__ Ya, const unsigned short* __restrict__ Xa,
    const unsigned short* __restrict__ BtK0, const unsigned short* __restrict__ BtV0,
    const unsigned short* __restrict__ BtK1, const unsigned short* __restrict__ BtV1,
    const float* __restrict__ bk0, const float* __restrict__ bv0,
    const float* __restrict__ bk1, const float* __restrict__ bv1,
    unsigned short* __restrict__ K0, unsigned short* __restrict__ V0t,
    unsigned short* __restrict__ K1, unsigned short* __restrict__ V1t)
{
    const int K = 512;
    __shared__ short As[2][128 * 64];
    __shared__ short Bs[2][64 * 64];

    const int z = blockIdx.z;
    const unsigned short* A  = (z < 2) ? Ya : Xa;
    const unsigned short* Bt = (z == 0) ? BtK0 : (z == 1) ? BtV0 : (z == 2) ? BtK1 : BtV1;
    const float* bias        = (z == 0) ? bk0 : (z == 1) ? bv0 : (z == 2) ? bk1 : bv1;
    const int trans = z & 1;

    const int t = threadIdx.x;
    const int lane = t & 63;
    const int wave = t >> 6;

    const int lid = blockIdx.x + 8 * blockIdx.y;
    const int wid = (lid & 7) * 64 + (lid >> 3);
    const int bm = (wid >> 3) * 128;
    const int bn = (wid & 7) * 64;

    const int wm = (wave >> 1) * 64;
    const int wn = (wave & 1) * 32;

    f32x4 acc[4][2] = {};
    const int srcslot = (((lane & 7) ^ (lane >> 3)) << 3);
    const int rsub = lane >> 3;

    auto stage = [&](int k0, int buf) {
#pragma unroll
        for (int i = 0; i < 4; ++i) {
            const int row = i * 32 + wave * 8 + rsub;
            const unsigned short* ga = A + (size_t)(bm + row) * K + k0 + srcslot;
            __builtin_amdgcn_global_load_lds(
                (const __attribute__((address_space(1))) unsigned int*)ga,
                (__attribute__((address_space(3))) unsigned int*)(&As[buf][(i * 256 + wave * 64) * 8]),
                16, 0, 0);
        }
#pragma unroll
        for (int i = 0; i < 2; ++i) {
            const int row = i * 32 + wave * 8 + rsub;
            const unsigned short* gb = Bt + (size_t)(bn + row) * K + k0 + srcslot;
            __builtin_amdgcn_global_load_lds(
                (const __attribute__((address_space(1))) unsigned int*)gb,
                (__attribute__((address_space(3))) unsigned int*)(&Bs[buf][(i * 256 + wave * 64) * 8]),
                16, 0, 0);
        }
    };

    const int fr = lane & 15;
    const int quad = lane >> 4;
    const int sw = (fr & 7) << 3;
    const int nk = K >> 6;

    stage(0, 0);
    __syncthreads();

    for (int it = 0; it < nk; ++it) {
        const int buf = it & 1;
        if (it + 1 < nk) stage((it + 1) << 6, buf ^ 1);
        frag16 af[2][4], bfr[2][2];
#pragma unroll
        for (int ks = 0; ks < 2; ++ks) {
            const int col = (ks * 32 + quad * 8) ^ sw;
#pragma unroll
            for (int i = 0; i < 4; ++i)
                af[ks][i] = *(const frag16*)(&As[buf][(wm + i * 16 + fr) * 64 + col]);
#pragma unroll
            for (int i = 0; i < 2; ++i)
                bfr[ks][i] = *(const frag16*)(&Bs[buf][(wn + i * 16 + fr) * 64 + col]);
        }
#pragma unroll
        for (int ks = 0; ks < 2; ++ks)
#pragma unroll
            for (int mi = 0; mi < 4; ++mi)
#pragma unroll
                for (int ni = 0; ni < 2; ++ni)
                    acc[mi][ni] = __builtin_amdgcn_mfma_f32_16x16x32_bf16(
                        af[ks][mi], bfr[ks][ni], acc[mi][ni], 0, 0, 0);
        __syncthreads();
    }

    if (trans) {
        unsigned short* CbT = (z == 1) ? V0t : V1t;
#pragma unroll
        for (int mi = 0; mi < 4; ++mi)
#pragma unroll
            for (int ni = 0; ni < 2; ++ni) {
                const int m = bm + wm + mi * 16 + quad * 4;
                const int n = bn + wn + ni * 16 + fr;
                ushort4v o;
#pragma unroll
                for (int r = 0; r < 4; ++r) o[r] = f2b(acc[mi][ni][r] + bias[n]);
                const int bb = m >> 9, s = m & 511;
                const int hh = n >> 6, dd = n & 63;
                *(ushort4v*)(CbT + (((size_t)((bb * Hdim + hh) * DKdim + dd)) << 9) + s) = o;
            }
    } else {
        unsigned short* Cb = (z == 0) ? K0 : K1;
#pragma unroll
        for (int mi = 0; mi < 4; ++mi)
#pragma unroll
            for (int r = 0; r < 4; ++r) {
                const int m = bm + wm + mi * 16 + quad * 4 + r;
#pragma unroll
                for (int ni = 0; ni < 2; ++ni) {
                    const int n = bn + wn + ni * 16 + fr;
                    Cb[(size_t)m * 512 + n] = f2b(acc[mi][ni][r] + bias[n]);
                }
            }
    }
}

// ---------------------------------------------------------------------------
// Dual O-projection (FULL-K, round-9 proven): z in {0,1} selects layer;
// C = A@Bt + bias + R (fp32). Same verified BK=64 swizzled core. K=512.
// ---------------------------------------------------------------------------
__global__ __launch_bounds__(256) void gemm_o2(
    const unsigned short* __restrict__ A0, const unsigned short* __restrict__ A1,
    const unsigned short* __restrict__ B0, const unsigned short* __restrict__ B1,
    const float* __restrict__ bias0, const float* __restrict__ bias1,
    const float* __restrict__ R0, const float* __restrict__ R1,
    float* __restrict__ C0, float* __restrict__ C1)
{
    const int K = 512;
    __shared__ short As[2][128 * 64];
    __shared__ short Bs[2][64 * 64];

    const int z = blockIdx.z;
    const unsigned short* A  = z ? A1 : A0;
    const unsigned short* Bt = z ? B1 : B0;
    const float* bias        = z ? bias1 : bias0;
    const float* R           = z ? R1 : R0;
    float* Cf                = z ? C1 : C0;

    const int t = threadIdx.x;
    const int lane = t & 63;
    const int wave = t >> 6;

    const int lid = blockIdx.x + 8 * blockIdx.y;
    const int wid = (lid & 7) * 64 + (lid >> 3);
    const int bm = (wid >> 3) * 128;
    const int bn = (wid & 7) * 64;

    const int wm = (wave >> 1) * 64;
    const int wn = (wave & 1) * 32;

    f32x4 acc[4][2] = {};
    const int srcslot = (((lane & 7) ^ (lane >> 3)) << 3);
    const int rsub = lane >> 3;

    auto stage = [&](int k0, int buf) {
#pragma unroll
        for (int i = 0; i < 4; ++i) {
            const int row = i * 32 + wave * 8 + rsub;
            const unsigned short* ga = A + (size_t)(bm + row) * K + k0 + srcslot;
            __builtin_amdgcn_global_load_lds(
                (const __attribute__((address_space(1))) unsigned int*)ga,
                (__attribute__((address_space(3))) unsigned int*)(&As[buf][(i * 256 + wave * 64) * 8]),
                16, 0, 0);
        }
#pragma unroll
        for (int i = 0; i < 2; ++i) {
            const int row = i * 32 + wave * 8 + rsub;
            const unsigned short* gb = Bt + (size_t)(bn + row) * K + k0 + srcslot;
            __builtin_amdgcn_global_load_lds(
                (const __attribute__((address_space(1))) unsigned int*)gb,
                (__attribute__((address_space(3))) unsigned int*)(&Bs[buf][(i * 256 + wave * 64) * 8]),
                16, 0, 0);
        }
    };

    const int fr = lane & 15;
    const int quad = lane >> 4;
    const int sw = (fr & 7) << 3;
    const int nk = K >> 6;

    stage(0, 0);
    __syncthreads();

    for (int it = 0; it < nk; ++it) {
        const int buf = it & 1;
        if (it + 1 < nk) stage((it + 1) << 6, buf ^ 1);
        frag16 af[2][4], bfr[2][2];
#pragma unroll
        for (int ks = 0; ks < 2; ++ks) {
            const int col = (ks * 32 + quad * 8) ^ sw;
#pragma unroll
            for (int i = 0; i < 4; ++i)
                af[ks][i] = *(const frag16*)(&As[buf][(wm + i * 16 + fr) * 64 + col]);
#pragma unroll
            for (int i = 0; i < 2; ++i)
                bfr[ks][i] = *(const frag16*)(&Bs[buf][(wn + i * 16 + fr) * 64 + col]);
        }
#pragma unroll
        for (int ks = 0; ks < 2; ++ks)
#pragma unroll
            for (int mi = 0; mi < 4; ++mi)
#pragma unroll
                for (int ni = 0; ni < 2; ++ni)
                    acc[mi][ni] = __builtin_amdgcn_mfma_f32_16x16x32_bf16(
                        af[ks][mi], bfr[ks][ni], acc[mi][ni], 0, 0, 0);
        __syncthreads();
    }

#pragma unroll
    for (int mi = 0; mi < 4; ++mi) {
#pragma unroll
        for (int r = 0; r < 4; ++r) {
            const int m = bm + wm + mi * 16 + quad * 4 + r;
#pragma unroll
            for (int ni = 0; ni < 2; ++ni) {
                const int n = bn + wn + ni * 16 + fr;
                Cf[(size_t)m * 512 + n] = acc[mi][ni][r] + bias[n] + R[(size_t)m * 512 + n];
            }
        }
    }
}

// ---------------------------------------------------------------------------
// PREP: all weight transposes (blocks 0..1599) + both input fp32->bf16
// converts (blocks 1600..5695) fused into one launch (overlaps their tails).
// ---------------------------------------------------------------------------
__global__ __launch_bounds__(256) void prep_all(
    const float* __restrict__ Wk, const float* __restrict__ Wv,
    const float* __restrict__ Wo, const float* __restrict__ W1,
    const float* __restrict__ W2, unsigned short* __restrict__ dst,
    const float* __restrict__ Y0f, unsigned short* __restrict__ Y0b,
    const float* __restrict__ X0f, unsigned short* __restrict__ X0b,
    int convBlocks)
{
    const int bid = blockIdx.x;
    if (bid >= 1600) {
        const int cb = bid - 1600;
        const float* X = (cb < convBlocks) ? Y0f : X0f;
        unsigned short* Y = (cb < convBlocks) ? Y0b : X0b;
        const int lb = (cb < convBlocks) ? cb : cb - convBlocks;
        const size_t i = ((size_t)lb * 256 + threadIdx.x) * 8;
        float4 a = *(const float4*)(X + i);
        float4 b = *(const float4*)(X + i + 4);
        ushort8 o;
        o[0] = f2b(a.x); o[1] = f2b(a.y); o[2] = f2b(a.z); o[3] = f2b(a.w);
        o[4] = f2b(b.x); o[5] = f2b(b.y); o[6] = f2b(b.z); o[7] = f2b(b.w);
        *(ushort8*)(Y + i) = o;
        return;
    }

    const float* src; unsigned short* d; int K, N, tk, tn;
    if (bid < 576) {
        const int mat = bid >> 6, tile = bid & 63;
        const int l = mat / 3, wch = mat % 3;
        const float* W = (wch == 0) ? Wk : (wch == 1) ? Wv : Wo;
        src = W + (size_t)l * 262144;
        d = dst + (size_t)mat * 262144;
        K = 512; N = 512; tn = tile & 7; tk = tile >> 3;
    } else if (bid < 1088) {
        const int idx = bid - 576, l2 = idx >> 8, tile = idx & 255;
        src = W1 + (size_t)(l2 * 2) * (512 * 2048);
        d = dst + 9 * 262144 + (size_t)l2 * (512 * 2048);
        K = 512; N = 2048; tn = tile & 31; tk = tile >> 5;
    } else {
        const int idx = bid - 1088, l2 = idx >> 8, tile = idx & 255;
        src = W2 + (size_t)(l2 * 2) * (2048 * 512);
        d = dst + 9 * 262144 + 2 * (512 * 2048) + (size_t)l2 * (2048 * 512);
        K = 2048; N = 512; tn = tile & 7; tk = tile >> 3;
    }
    const int n0 = tn * 64, k0 = tk * 64;
    __shared__ float T[64][65];
    const int t = threadIdx.x;
    const int kl = t >> 4, n4 = (t & 15) << 2;
#pragma unroll
    for (int it = 0; it < 4; ++it) {
        const int k = kl + it * 16;
        float4 v = *(const float4*)(src + (size_t)(k0 + k) * N + n0 + n4);
        T[n4 + 0][k] = v.x; T[n4 + 1][k] = v.y;
        T[n4 + 2][k] = v.z; T[n4 + 3][k] = v.w;
    }
    __syncthreads();
    const int nl = t >> 3, k8 = (t & 7) << 3;
#pragma unroll
    for (int it = 0; it < 2; ++it) {
        const int n = nl + it * 32;
        ushort8 o;
#pragma unroll
        for (int c = 0; c < 8; ++c) o[c] = f2b(T[n][k8 + c]);
        *(ushort8*)(d + (size_t)(n0 + n) * K + k0 + k8) = o;
    }
}

// ---------------------------------------------------------------------------
// Flash-style monotonic attention v10: v9 (4-way j-split, LPT, dual-layer,
// 32-bit offsets) + pass-2 u-loop unrolled by 2 — iterations are fully
// independent (no barriers in the loop), so a 2-deep unroll gives the
// scheduler two long dependency chains to interleave (MFMA || VALU || LDS).
// ---------------------------------------------------------------------------
__global__ __launch_bounds__(256, 8) void attn_flash10(
    const unsigned short* __restrict__ Kb0, const unsigned short* __restrict__ Vt0,
    const unsigned short* __restrict__ Kb1, const unsigned short* __restrict__ Vt1,
    const float* __restrict__ gam,           // base; layer adds Hdim
    unsigned short* __restrict__ Ob0, unsigned short* __restrict__ Ob1,
    int mask_type, int dual)
{
    __shared__ float CTw[16 * 33];               // cross-tile strict suffix
    __shared__ unsigned short Pst[4][16 * 36];   // P staging (A-frag layout, per wave)
    __shared__ float S1s[4][16];                 // sum1 partials [w][row]
    __shared__ float S2s[4][16];                 // sum2 partials
    __shared__ float OaccA[16 * 66];             // oacc combine buffers
    __shared__ float OaccB[16 * 66];

    int bh, layer;
    if (dual) { layer = blockIdx.x & 1; bh = blockIdx.x >> 1; }
    else      { layer = 0;              bh = blockIdx.x; }
    const unsigned short* Kb = layer ? Kb1 : Kb0;
    const unsigned short* Vt = layer ? Vt1 : Vt0;
    unsigned short* Ob       = layer ? Ob1 : Ob0;
    const float* g           = gam + layer * Hdim;

    const int h = bh & 7, b = bh >> 3;
    const int rk = blockIdx.y;                   // LPT rank: 0 = heaviest
    const int tile = mask_type ? (31 - rk) : (rk == 0 ? 0 : 32 - rk);

    const int t = threadIdx.x, lane = t & 63, w = t >> 6;   // w: j-split slot
    const int quad = lane >> 4, fr = lane & 15;
    const int q0 = tile * 16;
    const int iRow = q0 + fr;                // this lane's q row

    const unsigned short* kbase = Kb + (size_t)b * Sdim * Ddim + h * DKdim;   // uniform
    const unsigned short* vtb = Vt + (size_t)(b * Hdim + h) * DKdim * Sdim;   // uniform
    const float gneg2 = -log1pf(__expf(g[h])) * 1.4426950408889634f;

    // 32-bit lane offsets (shorts); Ddim == Sdim == 512
    const unsigned lane_off = ((unsigned)fr << 9) + (unsigned)quad * 8;
    const unsigned kvstep = 16u * Ddim;      // 8192 shorts per jn-tile

    // Q as B-operand: rows q0+fr
    frag16 aq0 = *(const frag16*)(kbase + ((unsigned)q0 << 9) + lane_off);
    frag16 aq1 = *(const frag16*)(kbase + ((unsigned)q0 << 9) + lane_off + 32);

    // ---- Pass 1: sum1 partials + per-tile totals into CT (4-way jn split)
    float psum = 0.f;
    {
        unsigned ko = (unsigned)w * kvstep + lane_off;
        for (int jn = w; jn <= tile; jn += 4, ko += 4 * kvstep) {
            frag16 k0 = *(const frag16*)(kbase + ko);
            frag16 k1 = *(const frag16*)(kbase + ko + 32);
            f32x4 z = {0.f, 0.f, 0.f, 0.f};
            z = __builtin_amdgcn_mfma_f32_16x16x32_bf16(k0, aq0, z, 0, 0, 0);
            z = __builtin_amdgcn_mfma_f32_16x16x32_bf16(k1, aq1, z, 0, 0, 0);
            float tq = 0.f;
            if (jn < tile) {                 // fully-valid tile (both masks)
#pragma unroll
                for (int r = 0; r < 4; ++r) tq += EXP2(z[r] * SC2);
            } else {                         // diagonal tile
#pragma unroll
                for (int r = 0; r < 4; ++r) {
                    const bool valid = mask_type ? (quad * 4 + r <= fr)
                                                 : (quad * 4 + r < fr);
                    tq += valid ? EXP2(z[r] * SC2) : 0.f;
                }
            }
            psum += tq;
            float tt = tq;
            tt += __shfl_xor(tt, 16);
            tt += __shfl_xor(tt, 32);
            if (quad == 0) CTw[fr * 33 + jn] = tt;
        }
    }
    {
        float s1 = psum;
        s1 += __shfl_xor(s1, 16);
        s1 += __shfl_xor(s1, 32);
        if (lane < 16) S1s[w][lane] = s1;
    }
    __syncthreads();

    // totals -> strict cross-tile suffix (wave 0; rows by lanes 0..15)
    if (w == 0 && lane < 16) {
        float run = 0.f;
        for (int jn = tile; jn >= 0; --jn) {
            const float tv = CTw[lane * 33 + jn];
            CTw[lane * 33 + jn] = run;
            run += tv;
        }
    }
    __syncthreads();

    const float rsum1 = 1.f / (S1s[0][fr] + S1s[1][fr] + S1s[2][fr] + S1s[3][fr]);
    unsigned short* Pw = Pst[w];
    const bool fm_blk = (mask_type == 0) && (tile == 0);
    const bool fmrow = fm_blk && (fr == 0);
    const int umax = fm_blk ? (Sdim / 32 - 1) : (tile >> 1);
    float sum2p = 0.f;
    f32x4 oacc[4] = {};

    // ---- Pass 2: independent u-tiles, 4-way split, online PV
#pragma unroll 2
    for (int u = umax - w; u >= 0; u -= 4) {
        const unsigned ko2 = ((unsigned)u << 14) + lane_off;   // (2u)*8192
#pragma unroll
        for (int half = 0; half < 2; ++half) {
            const int jn = 2 * u + half;
            uint2 pku;
            if (jn > tile) {
                // empty tile: P=0, except mask0 row-0 uniform case (P=1)
                const unsigned int pv = fmrow ? 0x3F803F80u : 0u;
                pku.x = pv; pku.y = pv;
                sum2p += fmrow ? 4.f : 0.f;
            } else {
                const unsigned koh = ko2 + (unsigned)half * kvstep;
                frag16 k0 = *(const frag16*)(kbase + koh);
                frag16 k1 = *(const frag16*)(kbase + koh + 32);
                f32x4 z = {0.f, 0.f, 0.f, 0.f};
                z = __builtin_amdgcn_mfma_f32_16x16x32_bf16(k0, aq0, z, 0, 0, 0);
                z = __builtin_amdgcn_mfma_f32_16x16x32_bf16(k1, aq1, z, 0, 0, 0);
                const bool full = (jn < tile);   // wave-uniform
                float s2r[4], lsuf[4];
                float tq = 0.f;
#pragma unroll
                for (int r = 3; r >= 0; --r) {
                    lsuf[r] = tq;                // strict suffix within 4-run
                    s2r[r] = z[r] * SC2;
                    float e1 = EXP2(s2r[r]);
                    if (!full) {
                        const bool valid = mask_type ? (quad * 4 + r <= fr)
                                                     : (quad * 4 + r < fr);
                        e1 = valid ? e1 : 0.f;
                    }
                    tq += e1;
                }
                // strict suffix over quads (2 guarded shfl_down)
                float incl = tq;
                {
                    float u1 = __shfl_down(incl, 16);
                    incl += (quad < 3) ? u1 : 0.f;
                    float u2 = __shfl_down(incl, 32);
                    incl += (quad < 2) ? u2 : 0.f;
                }
                const float base = CTw[fr * 33 + jn] + (incl - tq);
                const float pos0 = (float)(iRow - (jn * 16 + quad * 4));
                float e2v[4];
#pragma unroll
                for (int r = 0; r < 4; ++r) {
                    const float ratio = (base + lsuf[r]) * rsum1;   // >= 0
                    const float arg = ratio * fabsf(pos0 - (float)r);
                    // sqrt via v_rsq: NaN-safe at arg==0
                    const float sq = arg * rsqrtf(fmaxf(arg, 1e-30f));
                    const float te = fmaxf(EXP2(gneg2 * sq), 1e-5f); // <= 1
                    float e2 = EXP2(s2r[r] * te);
                    if (!full) {
                        const bool valid = mask_type ? (quad * 4 + r <= fr)
                                                     : (quad * 4 + r < fr);
                        e2 = valid ? e2 : (fmrow ? 1.f : 0.f);
                    }
                    sum2p += e2;
                    e2v[r] = e2;
                }
                union { __hip_bfloat162 hh; unsigned int u; } c0, c1;
                c0.hh = __float22bfloat162_rn(make_float2(e2v[0], e2v[1]));
                c1.hh = __float22bfloat162_rn(make_float2(e2v[2], e2v[3]));
                pku.x = c0.u; pku.y = c1.u;
            }
            *(uint2*)(Pw + fr * 36 + half * 16 + quad * 4) = pku;
        }
        // PV over this pair's 32-wide window (A = P from LDS, B = Vt)
        frag16 pf = *(const frag16*)(Pw + fr * 36 + quad * 8);
        const unsigned vo = lane_off + ((unsigned)u << 5);   // fr*512 + quad*8 + u*32
#pragma unroll
        for (int dt = 0; dt < 4; ++dt) {
            frag16 vf = *(const frag16*)(vtb + vo + (unsigned)dt * 8192u);
            oacc[dt] = __builtin_amdgcn_mfma_f32_16x16x32_bf16(pf, vf, oacc[dt], 0, 0, 0);
        }
    }

    // ---- combine the four waves' partials (2-step tree through 2 buffers)
    {
        float s2 = sum2p;
        s2 += __shfl_xor(s2, 16);
        s2 += __shfl_xor(s2, 32);
        if (lane < 16) S2s[w][lane] = s2;
    }
    if (w == 1) {
#pragma unroll
        for (int dt = 0; dt < 4; ++dt)
#pragma unroll
            for (int r = 0; r < 4; ++r)
                OaccA[(quad * 4 + r) * 66 + dt * 16 + fr] = oacc[dt][r];
    }
    if (w == 3) {
#pragma unroll
        for (int dt = 0; dt < 4; ++dt)
#pragma unroll
            for (int r = 0; r < 4; ++r)
                OaccB[(quad * 4 + r) * 66 + dt * 16 + fr] = oacc[dt][r];
    }
    __syncthreads();
    if (w == 0) {
#pragma unroll
        for (int dt = 0; dt < 4; ++dt)
#pragma unroll
            for (int r = 0; r < 4; ++r)
                oacc[dt][r] += OaccA[(quad * 4 + r) * 66 + dt * 16 + fr];
    }
    if (w == 2) {
#pragma unroll
        for (int dt = 0; dt < 4; ++dt)
#pragma unroll
            for (int r = 0; r < 4; ++r)
                oacc[dt][r] += OaccB[(quad * 4 + r) * 66 + dt * 16 + fr];
    }
    __syncthreads();
    if (w == 2) {
#pragma unroll
        for (int dt = 0; dt < 4; ++dt)
#pragma unroll
            for (int r = 0; r < 4; ++r)
                OaccA[(quad * 4 + r) * 66 + dt * 16 + fr] = oacc[dt][r];
    }
    __syncthreads();

    if (w == 0) {
        const float rs2 = 1.f / (S2s[0][fr] + S2s[1][fr] + S2s[2][fr] + S2s[3][fr]);
        float rs2q[4];
#pragma unroll
        for (int r = 0; r < 4; ++r) rs2q[r] = __shfl(rs2, quad * 4 + r);

        // O rows q0+quad*4+r, cols dt*16+fr
        unsigned short* obase = Ob + ((size_t)(b * Sdim + q0)) * Ddim + h * DKdim;
#pragma unroll
        for (int dt = 0; dt < 4; ++dt)
#pragma unroll
            for (int r = 0; r < 4; ++r) {
                const float v = oacc[dt][r] + OaccA[(quad * 4 + r) * 66 + dt * 16 + fr];
                obase[(size_t)(quad * 4 + r) * Ddim + dt * 16 + fr] = f2b(v * rs2q[r]);
            }
    }
}

// ---------------------------------------------------------------------------
// LayerNorm, WAVE-PER-ROW (no barriers): 64 lanes x 8 f32, 12 shfl_xor.
// Optional fp32 partial P fused-added to X (split-K combine). fp32 out
// (nullable) + bf16 out (nullable). 4 rows per 256-thread block.
// ---------------------------------------------------------------------------
__device__ __forceinline__ void ln_row_wave(
    const float* __restrict__ X, const float* __restrict__ P,
    const float* __restrict__ g, const float* __restrict__ bta,
    float* __restrict__ Y, unsigned short* __restrict__ Yb,
    int row, int lane)
{
    const size_t base = (size_t)row * Ddim + lane * 8;
    float4 a = *(const float4*)(X + base);
    float4 b = *(const float4*)(X + base + 4);
    if (P) {
        float4 pa = *(const float4*)(P + base);
        float4 pb = *(const float4*)(P + base + 4);
        a.x += pa.x; a.y += pa.y; a.z += pa.z; a.w += pa.w;
        b.x += pb.x; b.y += pb.y; b.z += pb.z; b.w += pb.w;
    }
    float s  = a.x + a.y + a.z + a.w + b.x + b.y + b.z + b.w;
    float s2 = a.x * a.x + a.y * a.y + a.z * a.z + a.w * a.w
             + b.x * b.x + b.y * b.y + b.z * b.z + b.w * b.w;
#pragma unroll
    for (int off = 1; off < 64; off <<= 1) {
        s  += __shfl_xor(s, off);
        s2 += __shfl_xor(s2, off);
    }
    const float mean = s * (1.f / Ddim);
    const float var = s2 * (1.f / Ddim) - mean * mean;
    const float rs = rsqrtf(var + 1e-5f);
    float4 ga = *(const float4*)(g + lane * 8);
    float4 gb = *(const float4*)(g + lane * 8 + 4);
    float4 ba = *(const float4*)(bta + lane * 8);
    float4 bb = *(const float4*)(bta + lane * 8 + 4);
    float y[8];
    y[0] = (a.x - mean) * rs * ga.x + ba.x;
    y[1] = (a.y - mean) * rs * ga.y + ba.y;
    y[2] = (a.z - mean) * rs * ga.z + ba.z;
    y[3] = (a.w - mean) * rs * ga.w + ba.w;
    y[4] = (b.x - mean) * rs * gb.x + bb.x;
    y[5] = (b.y - mean) * rs * gb.y + bb.y;
    y[6] = (b.z - mean) * rs * gb.z + bb.z;
    y[7] = (b.w - mean) * rs * gb.w + bb.w;
    if (Y) {
        *(float4*)(Y + base)     = make_float4(y[0], y[1], y[2], y[3]);
        *(float4*)(Y + base + 4) = make_float4(y[4], y[5], y[6], y[7]);
    }
    if (Yb) {
        ushort8 o;
#pragma unroll
        for (int c = 0; c < 8; ++c) o[c] = f2b(y[c]);
        *(ushort8*)(Yb + base) = o;
    }
}

__global__ __launch_bounds__(256) void ln_w1(
    const float* __restrict__ X, const float* __restrict__ P,
    const float* __restrict__ g, const float* __restrict__ bta,
    float* __restrict__ Y, unsigned short* __restrict__ Yb)
{
    const int row = blockIdx.x * 4 + (threadIdx.x >> 6);
    ln_row_wave(X, P, g, bta, Y, Yb, row, threadIdx.x & 63);
}

// dual-tensor LN (no partials): rows [0,Mrows) set a, rest set b
__global__ __launch_bounds__(256) void ln_w2(
    const float* __restrict__ Xa, const float* __restrict__ ga,
    const float* __restrict__ ba, float* __restrict__ Ya,
    unsigned short* __restrict__ Yba,
    const float* __restrict__ Xb, const float* __restrict__ gb,
    const float* __restrict__ bb, float* __restrict__ Yb2,
    unsigned short* __restrict__ Ybb)
{
    const int row = blockIdx.x * 4 + (threadIdx.x >> 6);
    if (row < Mrows)
        ln_row_wave(Xa, nullptr, ga, ba, Ya, Yba, row, threadIdx.x & 63);
    else
        ln_row_wave(Xb, nullptr, gb, bb, Yb2, Ybb, row - Mrows, threadIdx.x & 63);
}

// ---------------------------------------------------------------------------
extern "C" void kernel_launch(void* const* d_in, const int* in_sizes, int n_in,
                              void* d_out, int out_size, void* d_ws, size_t ws_size,
                              hipStream_t stream)
{
    const float* x0     = (const float*)d_in[0];
    const float* y0     = (const float*)d_in[1];
    const float* Wk     = (const float*)d_in[2];
    const float* bk     = (const float*)d_in[3];
    const float* Wv     = (const float*)d_in[4];
    const float* bv     = (const float*)d_in[5];
    const float* Wo     = (const float*)d_in[6];
    const float* bo     = (const float*)d_in[7];
    const float* gammas = (const float*)d_in[8];
    const float* ln1g   = (const float*)d_in[9];
    const float* ln1b   = (const float*)d_in[10];
    const float* W1     = (const float*)d_in[11];
    const float* b1     = (const float*)d_in[12];
    const float* W2     = (const float*)d_in[13];
    const float* b2     = (const float*)d_in[14];
    const float* ln2g   = (const float*)d_in[15];
    const float* ln2b   = (const float*)d_in[16];

    const size_t NBSD = (size_t)Mrows * Ddim;   // 4,194,304
    float* ws = (float*)d_ws;
    float* T1   = ws;
    float* X1   = T1 + NBSD;
    float* Xbuf = X1 + NBSD;
    unsigned short* Kbf = (unsigned short*)(Xbuf + NBSD);
    unsigned short* Vt  = Kbf + NBSD;
    unsigned short* AOb = Vt + NBSD;
    unsigned short* Abf = AOb + NBSD;
    unsigned short* Xbf = Abf + NBSD;
    unsigned short* Ybf = Xbf + NBSD;
    unsigned short* Hbb = Ybf + NBSD;                       // [M,F] = 4 NBSD units
    unsigned short* WtAll = Hbb + (size_t)Mrows * Fdim;

    // transient aliases (all regions dead at their aliased use time):
    unsigned short* Xb_in = Hbb;                 // bf16(x0), consumed by kv4
    unsigned short* AOb1  = Hbb + NBSD;          // layer-1 attention out
    unsigned short* Yb_in = Hbb + 2 * NBSD;      // bf16(y0), consumed by kv4
    unsigned short* Kbf1  = Abf;                 // layer-1 K (dead until LN writes Abf)
    unsigned short* Vt1   = Ybf;                 // layer-1 Vt (dead until LN2_0 writes Ybf)
    float* T1b = (float*)d_out;                  // layer-1 O out (dead until final LN)
    float* P1  = (float*)AOb;                    // FFN2 split-K partial (AOb+Abf dead there)

    auto WtK = [&](int l) { return WtAll + (size_t)(l * 3 + 0) * 262144; };
    auto WtV = [&](int l) { return WtAll + (size_t)(l * 3 + 1) * 262144; };
    auto WtO = [&](int l) { return WtAll + (size_t)(l * 3 + 2) * 262144; };
    auto Wt1 = [&](int l) { return WtAll + 9 * 262144 + (size_t)(l >> 1) * (512 * 2048); };
    auto Wt2 = [&](int l) { return WtAll + 9 * 262144 + 2 * (512 * 2048) + (size_t)(l >> 1) * (2048 * 512); };

    const int convBlocks = (int)(NBSD / 2048);   // 2048

    // 1. weight transposes + input converts (single launch)
    prep_all<<<1600 + 2 * convBlocks, 256, 0, stream>>>(
        Wk, Wv, Wo, W1, W2, WtAll, y0, Yb_in, x0, Xb_in, convBlocks);
    // 2. KV projections for layers 0 and 1 (one launch, z=0..3)
    gemm_kv4<<<dim3(8, 64, 4), 256, 0, stream>>>(
        Yb_in, Xb_in, WtK(0), WtV(0), WtK(1), WtV(1),
        bk, bv, bk + Ddim, bv + Ddim,
        Kbf, Vt, Kbf1, Vt1);
    // 3. attention layers 0+1 merged (mask1 both; layer interleaved in x)
    attn_flash10<<<dim3(2 * Bdim * Hdim, Sdim / 16, 1), 256, 0, stream>>>(
        Kbf, Vt, Kbf1, Vt1, gammas, AOb, AOb1, 1, 1);
    // 4. O-projections + residual for layers 0+1 (one launch, full-K)
    gemm_o2<<<dim3(8, 64, 2), 256, 0, stream>>>(
        AOb, AOb1, WtO(0), WtO(1), bo, bo + Ddim, y0, x0, T1, T1b);
    // 5. LN1 for both layers: L0 -> X1 + Abf; L1 -> Xbuf + Xbf (final)
    ln_w2<<<2 * Mrows / 4, 256, 0, stream>>>(
        T1, ln1g, ln1b, X1, Abf,
        T1b, ln1g + Ddim, ln1b + Ddim, Xbuf, Xbf);
    // 6-8. block-0 FFN (FFN2 split-K=2, LN combines) + LN2 -> Ybf
    gemm_mfma<<<dim3(Fdim / 128, Mrows / 128), 256, 0, stream>>>(
        (const __hip_bfloat16*)Abf, (const __hip_bfloat16*)Wt1(0),
        b1, nullptr, nullptr, Hbb, Mrows, Fdim, Ddim, 1);
    gemm_splitk<<<dim3(8, 64, 2), 256, 0, stream>>>(
        Hbb, Wt2(0), b2, X1, T1, P1, 2048, 1024);
    ln_w1<<<Mrows / 4, 256, 0, stream>>>(T1, P1, ln2g, ln2b, nullptr, Ybf);

    // ---- block 2: knowledge retriever (q/k = x-out, v = y-out, mask0, FFN)
    const int l = 2;
    // 9. KV (dual z): K from Xbf, V from Ybf
    gemm_n64<<<dim3(8, 64, 2), 256, 0, stream>>>(
        Xbf, Ybf, WtK(l), WtV(l), bk + l * Ddim, bv + l * Ddim,
        nullptr, nullptr, Kbf, Vt, Ddim);
    // 10. attention (mask0, single layer)
    attn_flash10<<<dim3(Bdim * Hdim, Sdim / 16, 1), 256, 0, stream>>>(
        Kbf, Vt, Kbf, Vt, gammas + (size_t)l * Hdim, AOb, AOb, 0, 0);
    // 11. O-projection + residual (Xbuf), full-K
    gemm_n64<<<dim3(8, 64, 1), 256, 0, stream>>>(
        AOb, AOb, WtO(l), WtO(l), bo + l * Ddim, bo + l * Ddim,
        Xbuf, T1, nullptr, nullptr, Ddim);
    // 12. LN1 -> X1 + Abf
    ln_w1<<<Mrows / 4, 256, 0, stream>>>(T1, nullptr,
        ln1g + (size_t)l * Ddim, ln1b + (size_t)l * Ddim, X1, Abf);
    // 13-15. FFN (split-K FFN2) + LN2 -> d_out (fp32)
    gemm_mfma<<<dim3(Fdim / 128, Mrows / 128), 256, 0, stream>>>(
        (const __hip_bfloat16*)Abf, (const __hip_bfloat16*)Wt1(l),
        b1 + (size_t)l * Fdim, nullptr, nullptr, Hbb, Mrows, Fdim, Ddim, 1);
    gemm_splitk<<<dim3(8, 64, 2), 256, 0, stream>>>(
        Hbb, Wt2(l), b2 + (size_t)l * Ddim, X1, T1, P1, 2048, 1024);
    ln_w1<<<Mrows / 4, 256, 0, stream>>>(T1, P1,
        ln2g + (size_t)l * Ddim, ln2b + (size_t)l * Ddim, (float*)d_out, nullptr);
}